// Round 18
// baseline (374.140 us; speedup 1.0000x reference)
//
#include <hip/hip_runtime.h>

// ---------------------------------------------------------------------------
// SLAYER SNN on MI355X — layer 1 on i8 MATRIX CORES, exact integer limbs.
//   q[o,f] = rint(W1[o,f]*2^27) == l0 + 256 l1 + 65536 l2 + 2^24 l3 (signed
//   i8 limbs, exact). z*2^27 = sum_l 2^(8l) * (limb_l GEMM x), x in {0,1},
//   v_mfma_i32_32x32x32_i8 (exact). M limb-interleaved (m=o*4+l) -> limbs
//   combine in-register (wrapping u32, exact since |s| < 2^31); 8 i32 kc
//   planes sum exactly in i64 in redpsp1. z integer-identical throughout.
// Round 18: bitpack = ballot + REGISTER CAPTURE + coalesced 512B stores
//   (round-17's lane-0 8B stores caused 8x write amplification / RMW
//   serialization). Lane l keeps ballot of inner-iter j=l>>2, comp q=l&3;
//   wave stores 64 consecutive t-words at once. 5 chunks x 2048 row-groups
//   = 10240 waves. Bits identical to the passing round-17.
// l2/l3: round-15 proven sparse_gemm + redpsp23.
// ---------------------------------------------------------------------------

#define B   8
#define T   300
#define F0  16384
#define O1  410
#define O2  240
#define OP2 240
#define O3  10
#define OP3 16
#define W1M 7             // u64 words per layer-1 mask (28 u16 slots)
#define W2M 4             // u64 words per layer-2 mask (16 u16 slots)
#define NCOLS (B*T)       // 2400
#define LCAP 2048
#define PPLC32 ((size_t)416 * NCOLS)   // i32 elements per kc plane

typedef int  int32x4  __attribute__((ext_vector_type(4)));
typedef int  int32x16 __attribute__((ext_vector_type(16)));

// 16 bits -> 16 bytes (0/1): byte i = bit i. Exactly the fragment pattern.
__device__ __forceinline__ int32x4 expand16(unsigned m)
{
    int32x4 r;
    r.x = (int)((((m      ) & 15u) * 0x00204081u) & 0x01010101u);
    r.y = (int)((((m >>  4) & 15u) * 0x00204081u) & 0x01010101u);
    r.z = (int)((((m >>  8) & 15u) * 0x00204081u) & 0x01010101u);
    r.w = (int)((((m >> 12) & 15u) * 0x00204081u) & 0x01010101u);
    return r;
}

// ---------------------------------------------------------------------------
// Fused prep: [0,2560) ballot-bitpack x (reg-capture, coalesced stores);
// [2560,4224) quant W1 limbs; [4224,4624) quant W2/W3. No LDS.
// Bbit u64: word(b,it,t) bit l = (x[b][it*64+l][t] != 0).
// ---------------------------------------------------------------------------
__global__ __launch_bounds__(256) void prep_kernel(
    const float* __restrict__ X,  const float* __restrict__ W1,
    const float* __restrict__ W2, const float* __restrict__ W3,
    unsigned long long* __restrict__ Bbit, char* __restrict__ Aswz,
    int* __restrict__ Q2T, int* __restrict__ Q3T)
{
    int bid = blockIdx.x;
    int tid = threadIdx.x;

    if (bid < 2560) {                            // ---- ballot bitpack ----
        int wid = bid * 4 + (tid >> 6);          // 0..10239
        int gw = wid / 5, c = wid % 5;           // gw = b*256+it, c = t-chunk
        int b = gw >> 8, it = gw & 255;
        int lane = tid & 63;
        const float* xp = X + ((size_t)b * F0 + it * 64 + lane) * T;

        int jcap = lane >> 2, qcap = lane & 3;
        unsigned long long st = 0;
        #pragma unroll
        for (int j = 0; j < 16; ++j) {
            int tq = c * 16 + j;                 // t = 4*tq .. 4*tq+3
            float4 v = make_float4(0.f, 0.f, 0.f, 0.f);
            if (tq < 75) v = *(const float4*)(xp + tq * 4);   // wave-uniform
            unsigned long long m0 = __ballot(v.x != 0.0f);
            unsigned long long m1 = __ballot(v.y != 0.0f);
            unsigned long long m2 = __ballot(v.z != 0.0f);
            unsigned long long m3 = __ballot(v.w != 0.0f);
            if (j == jcap)
                st = (qcap == 0) ? m0 : (qcap == 1) ? m1 : (qcap == 2) ? m2 : m3;
        }
        int t = c * 64 + lane;
        if (t < T)
            Bbit[(size_t)(b * 256 + it) * 320 + t] = st;   // 512B/wave coalesced

    } else if (bid < 4224) {                     // ---- quant W1 limbs ----
        int j = bid - 2560;                      // 0..1663
        int o  = j >> 2;
        int f0 = ((j & 3) * 256 + tid) * 16;

        float w[16];
        if (o < O1) {
            #pragma unroll
            for (int e = 0; e < 16; e += 4)
                *(float4*)&w[e] = *(const float4*)(W1 + (size_t)o * F0 + f0 + e);
        } else {
            #pragma unroll
            for (int e = 0; e < 16; ++e) w[e] = 0.0f;
        }

        unsigned pk[4][4] = {{0,0,0,0},{0,0,0,0},{0,0,0,0},{0,0,0,0}};
        #pragma unroll
        for (int e = 0; e < 16; ++e) {
            int q = (int)__double2ll_rn((double)w[e] * 134217728.0);   // 2^27
            int l0 = (int)(signed char)(q & 255);  q = (q - l0) >> 8;
            int l1 = (int)(signed char)(q & 255);  q = (q - l1) >> 8;
            int l2 = (int)(signed char)(q & 255);  int l3 = (q - l2) >> 8;
            pk[0][e >> 2] |= (unsigned)(l0 & 255) << (8 * (e & 3));
            pk[1][e >> 2] |= (unsigned)(l1 & 255) << (8 * (e & 3));
            pk[2][e >> 2] |= (unsigned)(l2 & 255) << (8 * (e & 3));
            pk[3][e >> 2] |= (unsigned)(l3 & 255) << (8 * (e & 3));
        }

        int kit = f0 >> 6, ks = (f0 >> 5) & 1, hb = (f0 >> 4) & 1;
        #pragma unroll
        for (int l = 0; l < 4; ++l) {
            int m = o * 4 + l;
            int mt = m >> 7, r = m & 127, g = r >> 5, row = r & 31;
            int word = ks * 64 + row + 32 * hb;
            size_t addr = ((size_t)(mt * 256 + kit) * 4 + g) * 2048 + (size_t)word * 16;
            *(int32x4*)(Aswz + addr) =
                (int32x4){(int)pk[l][0], (int)pk[l][1], (int)pk[l][2], (int)pk[l][3]};
        }

    } else {                                     // ---- quant W2/W3 ----
        int idx = (bid - 4224) * 256 + tid;
        const int n1 = O1 * OP2;                 // 98400
        const int n2 = O2 * OP3;                 // 3840
        if (idx < n1) {
            int f = idx / OP2, o = idx - f * OP2;
            Q2T[idx] = (int)__double2ll_rn((double)W2[(size_t)o * O1 + f] * 67108864.0);
        } else if (idx < n1 + n2) {
            int j = idx - n1;
            int f = j / OP3, o = j - f * OP3;
            double v = (o < O3) ? (double)W3[(size_t)o * O2 + f] : 0.0;
            Q3T[j] = (int)__double2ll_rn(v * 67108864.0);
        }
    }
}

// ---------------------------------------------------------------------------
// LDS-free i8 MFMA GEMM, copy-free 2-stage pipeline, kc=8 (round-15 proven).
// ---------------------------------------------------------------------------
__global__ __launch_bounds__(256) void mfma_gemm_kernel(
    const char* __restrict__ Aswz, const unsigned short* __restrict__ Bbit,
    int* __restrict__ Pc)
{
    int id  = blockIdx.x;
    int xcd = id & 7, rr = id >> 3;
    int bh  = rr & 15, gq = rr >> 4;
    int g   = xcd + 8 * gq;                      // 0..103, exact
    int mt = g >> 3, kc = g & 7;
    int b = bh >> 1, half = bh & 1;

    int tid = threadIdx.x;
    int lane = tid & 63, wv = tid >> 6;
    int wm = wv >> 1, wn = wv & 1;
    int ng0 = wn * 3;
    int nfr = wn ? 2 : 3;                        // wave-uniform

    const char* Ab = Aswz + ((size_t)(mt * 256 + kc * 32) * 4 + wm * 2) * 2048
                          + (size_t)lane * 16;
    const char* Bb = (const char*)Bbit + (size_t)(b * 256 + kc * 32) * 320 * 8;
    int hb16 = (lane >> 5) * 16;

    const char* Bf[3];
    #pragma unroll
    for (int fn = 0; fn < 3; ++fn) {
        int colf = (half * 5 + ng0 + fn) * 32 + (lane & 31);
        Bf[fn] = Bb + (size_t)colf * 8;
    }

    int32x16 acc[2][3];
    #pragma unroll
    for (int fm = 0; fm < 2; ++fm)
        #pragma unroll
        for (int fn = 0; fn < 3; ++fn)
            acc[fm][fn] = (int32x16){0,0,0,0,0,0,0,0,0,0,0,0,0,0,0,0};

    int32x4 aA[2][2], aB[2][2];
    uint2   rA[3],    rB[3];

#define LOAD_STAGE(AR, RR, ITN)                                               \
    { const char* Abn_ = Ab + (size_t)(ITN) * 8192;                           \
      AR[0][0] = *(const int32x4*)(Abn_);                                     \
      AR[0][1] = *(const int32x4*)(Abn_ + 1024);                              \
      AR[1][0] = *(const int32x4*)(Abn_ + 2048);                              \
      AR[1][1] = *(const int32x4*)(Abn_ + 3072);                              \
      _Pragma("unroll")                                                       \
      for (int fn_ = 0; fn_ < 3; ++fn_)                                       \
          if (fn_ < nfr)                                                      \
              RR[fn_] = *(const uint2*)(Bf[fn_] + (size_t)(ITN) * 2560); }

#define COMPUTE_STAGE(AR, RR)                                                 \
    { _Pragma("unroll")                                                       \
      for (int ks_ = 0; ks_ < 2; ++ks_)                                       \
          _Pragma("unroll")                                                   \
          for (int fn_ = 0; fn_ < 3; ++fn_)                                   \
              if (fn_ < nfr) {                                                \
                  unsigned mraw_ = ks_ ? RR[fn_].y : RR[fn_].x;               \
                  int32x4 bvv_ = expand16((mraw_ >> hb16) & 0xFFFFu);         \
                  acc[0][fn_] = __builtin_amdgcn_mfma_i32_32x32x32_i8(        \
                      AR[0][ks_], bvv_, acc[0][fn_], 0, 0, 0);                \
                  acc[1][fn_] = __builtin_amdgcn_mfma_i32_32x32x32_i8(        \
                      AR[1][ks_], bvv_, acc[1][fn_], 0, 0, 0);                \
              } }

    LOAD_STAGE(aA, rA, 0);
    for (int it = 0; it < 32; it += 2) {
        LOAD_STAGE(aB, rB, it + 1);              // it+1 <= 31 always
        COMPUTE_STAGE(aA, rA);
        int itn2 = (it + 2 < 32) ? it + 2 : 31;  // last prefetch harmless
        LOAD_STAGE(aA, rA, itn2);
        COMPUTE_STAGE(aB, rB);
    }
#undef LOAD_STAGE
#undef COMPUTE_STAGE

    // In-register limb combine in wrapping u32 (exact: |s| < 2^31) -> i32.
    int col = lane & 31, h = lane >> 5;
    int* Pk = Pc + (size_t)kc * PPLC32 + (size_t)b * T;
    #pragma unroll
    for (int fm = 0; fm < 2; ++fm) {
        #pragma unroll
        for (int fn = 0; fn < 3; ++fn) {
            if (fn >= nfr) continue;
            int t = (half * 5 + ng0 + fn) * 32 + col;
            if (t >= T) continue;
            int obase = mt * 32 + wm * 16 + fm * 8;
            #pragma unroll
            for (int q = 0; q < 4; ++q) {
                int o = obase + 2 * q + h;
                unsigned s = (unsigned)acc[fm][fn][4 * q]
                           + ((unsigned)acc[fm][fn][4 * q + 1] << 8)
                           + ((unsigned)acc[fm][fn][4 * q + 2] << 16)
                           + ((unsigned)acc[fm][fn][4 * q + 3] << 24);
                Pk[(size_t)o * NCOLS + t] = (int)s;
            }
        }
    }
}

// ---------------------------------------------------------------------------
// Layer 1: sum 8 i32 kc planes in i64 (exact) + psp conv + fused spike LIF.
// smask1: u16[col][28] (== u64[col][7]); slots 26,27 zeroed.
// ---------------------------------------------------------------------------
__global__ __launch_bounds__(320) void redpsp1_kernel(
    const int* __restrict__ Pc, unsigned short* __restrict__ smask)
{
    __shared__ double zs[16][304];
    __shared__ double us[16][304];
    __shared__ double eps[100];
    int og = blockIdx.x, b = blockIdx.y;
    int o0 = og * 16;
    int tid = threadIdx.x;
    const double sc27 = 1.0 / 134217728.0;

    if (tid < 100) {
        double td = (double)tid;
        eps[tid] = (td / 10.0) * exp(1.0 - td / 10.0);
    }
    if (tid < T) {
        size_t col = (size_t)b * T + tid;
        #pragma unroll 4
        for (int ol = 0; ol < 16; ++ol) {
            int o = o0 + ol;
            size_t idx = (size_t)o * NCOLS + col;
            long long s = 0;
            #pragma unroll
            for (int c = 0; c < 8; ++c)
                s += (long long)Pc[(size_t)c * PPLC32 + idx];
            zs[ol][tid] = (double)s * sc27;
        }
    }
    __syncthreads();

    if (tid < T) {
        double sum[16];
        #pragma unroll
        for (int o = 0; o < 16; ++o) sum[o] = 0.0;
        int kmax = tid < 99 ? tid : 99;
        for (int k = 0; k <= kmax; ++k) {
            double e = eps[k];
            #pragma unroll
            for (int o = 0; o < 16; ++o)
                sum[o] = fma(e, zs[o][tid - k], sum[o]);
        }
        #pragma unroll
        for (int o = 0; o < 16; ++o) us[o][tid] = sum[o];
    }
    if (og == 25 && tid < T) {     // zero mask bits 416..447
        size_t col = (size_t)b * T + tid;
        *(unsigned*)((char*)smask + (col * 28 + 26) * 2) = 0u;
    }
    __syncthreads();

    if (tid < 64) {
        int l = tid;
        bool act = (l < 16) && (o0 + l < O1);
        const double alpha = exp(-0.5);
        const double A31   = exp(-15.5);
        const double c0    = -10.0 * exp(1.0);
        double E = 0.0, G = 0.0;
        unsigned hist = 0u;
        for (int t = 0; t < T; ++t) {
            double uval = act ? us[l][t] : -1.0e300;
            double v = uval + c0 * G;
            bool sp = (v >= 10.0);
            unsigned long long bal = __ballot(sp);
            if (l == 0)
                smask[((size_t)b * T + t) * 28 + og] =
                    (unsigned short)(bal & 0xFFFFu);
            double sN  = sp ? 1.0 : 0.0;
            double s31 = ((hist >> 30) & 1u) ? 1.0 : 0.0;
            double Em  = E - A31 * s31;
            double Gm  = G - 31.0 * A31 * s31;
            G = alpha * (sN + Gm + Em);
            E = alpha * (sN + Em);
            hist = (hist << 1) | (sp ? 1u : 0u);
        }
    }
}

// ---------------------------------------------------------------------------
// Layers 2/3: reduce (i32 z, scale) + psp conv + fused spike (round-15).
// ---------------------------------------------------------------------------
template<int OPAD_, int O_, int SLOTS, int NOG, bool OUT>
__global__ __launch_bounds__(320) void redpsp23_kernel(
    const int* __restrict__ Z, unsigned short* __restrict__ smask,
    float* __restrict__ sout, double scale)
{
    __shared__ double zs[16][304];
    __shared__ double us[16][304];
    __shared__ double eps[100];
    int og = blockIdx.x, b = blockIdx.y;
    int o0 = og * 16;
    int tid = threadIdx.x;

    if (tid < 100) {
        double td = (double)tid;
        eps[tid] = (td / 10.0) * exp(1.0 - td / 10.0);
    }
    if (tid < T) {
        size_t col = (size_t)b * T + tid;
        #pragma unroll 4
        for (int ol = 0; ol < 16; ++ol) {
            int o = o0 + ol;
            double zv = (o < OPAD_) ? (double)Z[col * OPAD_ + o] * scale : 0.0;
            zs[ol][tid] = zv;
        }
    }
    __syncthreads();

    if (tid < T) {
        double sum[16];
        #pragma unroll
        for (int o = 0; o < 16; ++o) sum[o] = 0.0;
        int kmax = tid < 99 ? tid : 99;
        for (int k = 0; k <= kmax; ++k) {
            double e = eps[k];
            #pragma unroll
            for (int o = 0; o < 16; ++o)
                sum[o] = fma(e, zs[o][tid - k], sum[o]);
        }
        #pragma unroll
        for (int o = 0; o < 16; ++o) us[o][tid] = sum[o];
    }
    if (SLOTS > NOG && og == NOG - 1 && tid < T) {
        size_t col = (size_t)b * T + tid;
        #pragma unroll
        for (int s = NOG; s < SLOTS; ++s)
            smask[col * SLOTS + s] = 0;
    }
    __syncthreads();

    if (tid < 64) {
        int l = tid;
        bool act = (l < 16) && (o0 + l < O_);
        const double alpha = exp(-0.5);
        const double A31   = exp(-15.5);
        const double c0    = -10.0 * exp(1.0);
        double E = 0.0, G = 0.0;
        unsigned hist = 0u;
        for (int t = 0; t < T; ++t) {
            double uval = act ? us[l][t] : -1.0e300;
            double v = uval + c0 * G;
            bool sp = (v >= 10.0);
            unsigned long long bal = __ballot(sp);
            if (SLOTS > 0 && l == 0)
                smask[((size_t)b * T + t) * SLOTS + og] =
                    (unsigned short)(bal & 0xFFFFu);
            if (OUT && act)
                sout[((size_t)b * O_ + o0 + l) * T + t] = sp ? 1.0f : 0.0f;
            double sN  = sp ? 1.0 : 0.0;
            double s31 = ((hist >> 30) & 1u) ? 1.0 : 0.0;
            double Em  = E - A31 * s31;
            double Gm  = G - 31.0 * A31 * s31;
            G = alpha * (sN + Gm + Em);
            E = alpha * (sN + Em);
            hist = (hist << 1) | (sp ? 1u : 0u);
        }
    }
}

// ---------------------------------------------------------------------------
// Sparse integer GEMM for layers 2/3 (proven).
// ---------------------------------------------------------------------------
__global__ __launch_bounds__(128) void sparse_gemm_kernel(
    const int* __restrict__ QT, const unsigned long long* __restrict__ cmask,
    int* __restrict__ Z, int OPAD, int W, int CW, int cshift)
{
    __shared__ int lf[LCAP];
    __shared__ int wsum[2];

    int chunk = blockIdx.x & ((1 << cshift) - 1);
    int col   = blockIdx.x >> cshift;
    int tid   = threadIdx.x;

    int wbase = col * W + chunk * CW;
    unsigned long long w0 = (2 * tid     < CW) ? cmask[wbase + 2 * tid]     : 0ULL;
    unsigned long long w1 = (2 * tid + 1 < CW) ? cmask[wbase + 2 * tid + 1] : 0ULL;
    int my = __popcll(w0) + __popcll(w1);

    int scan = my;
    #pragma unroll
    for (int d = 1; d < 64; d <<= 1) {
        int v = __shfl_up(scan, d);
        if ((tid & 63) >= d) scan += v;
    }
    if ((tid & 63) == 63) wsum[tid >> 6] = scan;
    __syncthreads();
    int off = ((tid >= 64) ? wsum[0] : 0) + scan - my;
    int n = wsum[0] + wsum[1];

    int f0e = (chunk * CW + 2 * tid) * 64;
    unsigned long long m = w0;
    while (m) {
        int bit = __ffsll(m) - 1;
        if (off < LCAP) lf[off] = (f0e + bit) * OPAD;
        ++off; m &= m - 1;
    }
    m = w1; f0e += 64;
    while (m) {
        int bit = __ffsll(m) - 1;
        if (off < LCAP) lf[off] = (f0e + bit) * OPAD;
        ++off; m &= m - 1;
    }
    __syncthreads();
    if (n > LCAP) n = LCAP;

    if (tid * 4 < OPAD) {
        int o = tid * 4;
        const int* bq = QT + o;
        int a0 = 0, a1 = 0, a2 = 0, a3 = 0;
        int i = 0;
        for (; i + 8 <= n; i += 8) {
            int4 ia = *(const int4*)&lf[i];
            int4 ib = *(const int4*)&lf[i + 4];
            int e0 = __builtin_amdgcn_readfirstlane(ia.x);
            int e1 = __builtin_amdgcn_readfirstlane(ia.y);
            int e2 = __builtin_amdgcn_readfirstlane(ia.z);
            int e3 = __builtin_amdgcn_readfirstlane(ia.w);
            int e4 = __builtin_amdgcn_readfirstlane(ib.x);
            int e5 = __builtin_amdgcn_readfirstlane(ib.y);
            int e6 = __builtin_amdgcn_readfirstlane(ib.z);
            int e7 = __builtin_amdgcn_readfirstlane(ib.w);
            int4 q0 = *(const int4*)(bq + e0);
            int4 q1 = *(const int4*)(bq + e1);
            int4 q2 = *(const int4*)(bq + e2);
            int4 q3 = *(const int4*)(bq + e3);
            int4 q4 = *(const int4*)(bq + e4);
            int4 q5 = *(const int4*)(bq + e5);
            int4 q6 = *(const int4*)(bq + e6);
            int4 q7 = *(const int4*)(bq + e7);
            a0 += q0.x; a1 += q0.y; a2 += q0.z; a3 += q0.w;
            a0 += q1.x; a1 += q1.y; a2 += q1.z; a3 += q1.w;
            a0 += q2.x; a1 += q2.y; a2 += q2.z; a3 += q2.w;
            a0 += q3.x; a1 += q3.y; a2 += q3.z; a3 += q3.w;
            a0 += q4.x; a1 += q4.y; a2 += q4.z; a3 += q4.w;
            a0 += q5.x; a1 += q5.y; a2 += q5.z; a3 += q5.w;
            a0 += q6.x; a1 += q6.y; a2 += q6.z; a3 += q6.w;
            a0 += q7.x; a1 += q7.y; a2 += q7.z; a3 += q7.w;
        }
        for (; i < n; ++i) {
            int e = __builtin_amdgcn_readfirstlane(lf[i]);
            int4 q = *(const int4*)(bq + e);
            a0 += q.x; a1 += q.y; a2 += q.z; a3 += q.w;
        }
        int* zb = Z + ((size_t)chunk * NCOLS + col) * OPAD + o;
        *(int4*)zb = make_int4(a0, a1, a2, a3);
    }
}

// ---------------------------------------------------------------------------
extern "C" void kernel_launch(void* const* d_in, const int* in_sizes, int n_in,
                              void* d_out, int out_size, void* d_ws, size_t ws_size,
                              hipStream_t stream)
{
    const float* x  = (const float*)d_in[0];
    const float* W1 = (const float*)d_in[1];
    const float* W2 = (const float*)d_in[2];
    const float* W3 = (const float*)d_in[3];
    float* out = (float*)d_out;

    const size_t sz_Aswz   = (size_t)13 * 256 * 4 * 2048;      // 27.26 MB
    const size_t sz_Bbit   = (size_t)B * 256 * 320 * 8;        //  5.24 MB
    const size_t sz_Pc     = (size_t)8 * PPLC32 * 4;           // 31.95 MB
    const size_t sz_Q2T    = (size_t)O1 * OP2 * 4;             // 394 KB
    const size_t sz_Q3T    = (size_t)O2 * OP3 * 4;             //  15 KB
    const size_t sz_smask1 = (size_t)NCOLS * 28 * 2;           // 134 KB
    const size_t sz_smask2 = (size_t)NCOLS * 16 * 2;           //  77 KB

    char* p = (char*)d_ws;
    char*               Aswz   = p;                      p += sz_Aswz;
    unsigned long long* Bbit   = (unsigned long long*)p; p += sz_Bbit;
    int*                Pc     = (int*)p;  char* pa = p; p += sz_Pc;
    int*                Q2T    = (int*)p;                p += sz_Q2T;
    int*                Q3T    = (int*)p;                p += sz_Q3T;
    unsigned short*     smask1 = (unsigned short*)p;     p += sz_smask1;
    unsigned short*     smask2 = (unsigned short*)p;     p += sz_smask2;
    // z2/z3 alias Pc's region (Pc dead after redpsp1):
    int* z2 = (int*)pa;                                  pa += (size_t)NCOLS * OP2 * 4;
    int* z3 = (int*)pa;                                  pa += (size_t)NCOLS * OP3 * 4;

    const double sc26 = 1.0 / 67108864.0;

    // --- prep (fused, LDS-free, coalesced mask stores) ---
    prep_kernel<<<dim3(4624), dim3(256), 0, stream>>>(
        x, W1, W2, W3, Bbit, Aswz, Q2T, Q3T);

    // --- layer 1 (MFMA + fused psp/spike) ---
    mfma_gemm_kernel<<<dim3(1664), dim3(256), 0, stream>>>(
        Aswz, (const unsigned short*)Bbit, Pc);
    redpsp1_kernel<<<dim3(26, B), dim3(320), 0, stream>>>(Pc, smask1);

    // --- layer 2 ---
    sparse_gemm_kernel<<<dim3(NCOLS), dim3(128), 0, stream>>>(
        Q2T, (const unsigned long long*)smask1, z2, OP2, W1M, W1M, 0);
    redpsp23_kernel<OP2, O2, 16, 15, false><<<dim3(15, B), dim3(320), 0, stream>>>(
        z2, smask2, (float*)0, sc26);

    // --- layer 3 ---
    sparse_gemm_kernel<<<dim3(NCOLS), dim3(128), 0, stream>>>(
        Q3T, (const unsigned long long*)smask2, z3, OP3, W2M, W2M, 0);
    redpsp23_kernel<OP3, O3, 0, 1, true><<<dim3(1, B), dim3(320), 0, stream>>>(
        z3, (unsigned short*)0, out, sc26);
}

// Round 19
// 278.558 us; speedup vs baseline: 1.3431x; 1.3431x over previous
//
#include <hip/hip_runtime.h>

// ---------------------------------------------------------------------------
// SLAYER SNN on MI355X — layer 1 on i8 MATRIX CORES, exact integer limbs.
//   q[o,f] = rint(W1[o,f]*2^27) == l0 + 256 l1 + 65536 l2 + 2^24 l3 (signed
//   i8 limbs, exact). z*2^27 = sum_l 2^(8l) * (limb_l GEMM x), x in {0,1},
//   v_mfma_i32_32x32x32_i8 (exact). M limb-interleaved (m=o*4+l) -> limbs
//   combine in-register (wrapping u32, exact since |s| < 2^31); 8 i32 kc
//   planes sum exactly in i64 in redpsp1. z integer-identical throughout.
// Round 19 bitpack: round-17's streaming reads (1 wave per (b,it), lane
//   streams its own 1200B row -> FETCH ~110MB) + LDS-staged ballots +
//   block-coalesced 512B-burst stores (fixes r17's 8x write amplification
//   AND r18's 3.3x read amplification). Bits identical to passing rounds.
// Everything else: exact round-15 proven structure (260us baseline).
// ---------------------------------------------------------------------------

#define B   8
#define T   300
#define F0  16384
#define O1  410
#define O2  240
#define OP2 240
#define O3  10
#define OP3 16
#define W1M 7             // u64 words per layer-1 mask (28 u16 slots)
#define W2M 4             // u64 words per layer-2 mask (16 u16 slots)
#define NCOLS (B*T)       // 2400
#define LCAP 2048
#define PPLC32 ((size_t)416 * NCOLS)   // i32 elements per kc plane

typedef int  int32x4  __attribute__((ext_vector_type(4)));
typedef int  int32x16 __attribute__((ext_vector_type(16)));

// 16 bits -> 16 bytes (0/1): byte i = bit i. Exactly the fragment pattern.
__device__ __forceinline__ int32x4 expand16(unsigned m)
{
    int32x4 r;
    r.x = (int)((((m      ) & 15u) * 0x00204081u) & 0x01010101u);
    r.y = (int)((((m >>  4) & 15u) * 0x00204081u) & 0x01010101u);
    r.z = (int)((((m >>  8) & 15u) * 0x00204081u) & 0x01010101u);
    r.w = (int)((((m >> 12) & 15u) * 0x00204081u) & 0x01010101u);
    return r;
}

// ---------------------------------------------------------------------------
// Fused prep: [0,512) ballot-bitpack x (streaming reads, LDS-staged masks,
// coalesced block stores); [512,2176) quant W1 limbs; [2176,2576) W2/W3.
// Bbit u64: word (b*256+it)*320 + t, bit l = (x[b][it*64+l][t] != 0).
// ---------------------------------------------------------------------------
__global__ __launch_bounds__(256) void prep_kernel(
    const float* __restrict__ X,  const float* __restrict__ W1,
    const float* __restrict__ W2, const float* __restrict__ W3,
    unsigned long long* __restrict__ Bbit, char* __restrict__ Aswz,
    int* __restrict__ Q2T, int* __restrict__ Q3T)
{
    __shared__ unsigned long long lmask[4][304];
    int bid = blockIdx.x;
    int tid = threadIdx.x;

    if (bid < 512) {                             // ---- ballot bitpack ----
        int wvid = tid >> 6, lane = tid & 63;
        int gw = bid * 4 + wvid;                 // 0..2047 = b*256 + it
        int b  = gw >> 8, it = gw & 255;
        const float* xp = X + ((size_t)b * F0 + it * 64 + lane) * T;

        #pragma unroll 5
        for (int tq = 0; tq < 75; ++tq) {        // 75*4 = 300 = T
            float4 v = *(const float4*)(xp + tq * 4);
            unsigned long long m0 = __ballot(v.x != 0.0f);
            unsigned long long m1 = __ballot(v.y != 0.0f);
            unsigned long long m2 = __ballot(v.z != 0.0f);
            unsigned long long m3 = __ballot(v.w != 0.0f);
            if (lane == 0) {
                lmask[wvid][tq * 4 + 0] = m0;
                lmask[wvid][tq * 4 + 1] = m1;
                lmask[wvid][tq * 4 + 2] = m2;
                lmask[wvid][tq * 4 + 3] = m3;
            }
        }
        __syncthreads();
        // block-coalesced store: 4 waves x 300 words, 512B bursts
        for (int idx = tid; idx < 1200; idx += 256) {
            int w = idx / 300, t = idx - w * 300;
            Bbit[(size_t)(bid * 4 + w) * 320 + t] = lmask[w][t];
        }

    } else if (bid < 2176) {                     // ---- quant W1 limbs ----
        int j = bid - 512;                       // 0..1663
        int o  = j >> 2;
        int f0 = ((j & 3) * 256 + tid) * 16;

        float w[16];
        if (o < O1) {
            #pragma unroll
            for (int e = 0; e < 16; e += 4)
                *(float4*)&w[e] = *(const float4*)(W1 + (size_t)o * F0 + f0 + e);
        } else {
            #pragma unroll
            for (int e = 0; e < 16; ++e) w[e] = 0.0f;
        }

        unsigned pk[4][4] = {{0,0,0,0},{0,0,0,0},{0,0,0,0},{0,0,0,0}};
        #pragma unroll
        for (int e = 0; e < 16; ++e) {
            int q = (int)__double2ll_rn((double)w[e] * 134217728.0);   // 2^27
            int l0 = (int)(signed char)(q & 255);  q = (q - l0) >> 8;
            int l1 = (int)(signed char)(q & 255);  q = (q - l1) >> 8;
            int l2 = (int)(signed char)(q & 255);  int l3 = (q - l2) >> 8;
            pk[0][e >> 2] |= (unsigned)(l0 & 255) << (8 * (e & 3));
            pk[1][e >> 2] |= (unsigned)(l1 & 255) << (8 * (e & 3));
            pk[2][e >> 2] |= (unsigned)(l2 & 255) << (8 * (e & 3));
            pk[3][e >> 2] |= (unsigned)(l3 & 255) << (8 * (e & 3));
        }

        int kit = f0 >> 6, ks = (f0 >> 5) & 1, hb = (f0 >> 4) & 1;
        #pragma unroll
        for (int l = 0; l < 4; ++l) {
            int m = o * 4 + l;
            int mt = m >> 7, r = m & 127, g = r >> 5, row = r & 31;
            int word = ks * 64 + row + 32 * hb;
            size_t addr = ((size_t)(mt * 256 + kit) * 4 + g) * 2048 + (size_t)word * 16;
            *(int32x4*)(Aswz + addr) =
                (int32x4){(int)pk[l][0], (int)pk[l][1], (int)pk[l][2], (int)pk[l][3]};
        }

    } else {                                     // ---- quant W2/W3 ----
        int idx = (bid - 2176) * 256 + tid;
        const int n1 = O1 * OP2;                 // 98400
        const int n2 = O2 * OP3;                 // 3840
        if (idx < n1) {
            int f = idx / OP2, o = idx - f * OP2;
            Q2T[idx] = (int)__double2ll_rn((double)W2[(size_t)o * O1 + f] * 67108864.0);
        } else if (idx < n1 + n2) {
            int j = idx - n1;
            int f = j / OP3, o = j - f * OP3;
            double v = (o < O3) ? (double)W3[(size_t)o * O2 + f] : 0.0;
            Q3T[j] = (int)__double2ll_rn(v * 67108864.0);
        }
    }
}

// ---------------------------------------------------------------------------
// LDS-free i8 MFMA GEMM, copy-free 2-stage pipeline, kc=8 (round-15 proven).
// ---------------------------------------------------------------------------
__global__ __launch_bounds__(256) void mfma_gemm_kernel(
    const char* __restrict__ Aswz, const unsigned short* __restrict__ Bbit,
    int* __restrict__ Pc)
{
    int id  = blockIdx.x;
    int xcd = id & 7, rr = id >> 3;
    int bh  = rr & 15, gq = rr >> 4;
    int g   = xcd + 8 * gq;                      // 0..103, exact
    int mt = g >> 3, kc = g & 7;
    int b = bh >> 1, half = bh & 1;

    int tid = threadIdx.x;
    int lane = tid & 63, wv = tid >> 6;
    int wm = wv >> 1, wn = wv & 1;
    int ng0 = wn * 3;
    int nfr = wn ? 2 : 3;                        // wave-uniform

    const char* Ab = Aswz + ((size_t)(mt * 256 + kc * 32) * 4 + wm * 2) * 2048
                          + (size_t)lane * 16;
    const char* Bb = (const char*)Bbit + (size_t)(b * 256 + kc * 32) * 320 * 8;
    int hb16 = (lane >> 5) * 16;

    const char* Bf[3];
    #pragma unroll
    for (int fn = 0; fn < 3; ++fn) {
        int colf = (half * 5 + ng0 + fn) * 32 + (lane & 31);
        Bf[fn] = Bb + (size_t)colf * 8;
    }

    int32x16 acc[2][3];
    #pragma unroll
    for (int fm = 0; fm < 2; ++fm)
        #pragma unroll
        for (int fn = 0; fn < 3; ++fn)
            acc[fm][fn] = (int32x16){0,0,0,0,0,0,0,0,0,0,0,0,0,0,0,0};

    int32x4 aA[2][2], aB[2][2];
    uint2   rA[3],    rB[3];

#define LOAD_STAGE(AR, RR, ITN)                                               \
    { const char* Abn_ = Ab + (size_t)(ITN) * 8192;                           \
      AR[0][0] = *(const int32x4*)(Abn_);                                     \
      AR[0][1] = *(const int32x4*)(Abn_ + 1024);                              \
      AR[1][0] = *(const int32x4*)(Abn_ + 2048);                              \
      AR[1][1] = *(const int32x4*)(Abn_ + 3072);                              \
      _Pragma("unroll")                                                       \
      for (int fn_ = 0; fn_ < 3; ++fn_)                                       \
          if (fn_ < nfr)                                                      \
              RR[fn_] = *(const uint2*)(Bf[fn_] + (size_t)(ITN) * 2560); }

#define COMPUTE_STAGE(AR, RR)                                                 \
    { _Pragma("unroll")                                                       \
      for (int ks_ = 0; ks_ < 2; ++ks_)                                       \
          _Pragma("unroll")                                                   \
          for (int fn_ = 0; fn_ < 3; ++fn_)                                   \
              if (fn_ < nfr) {                                                \
                  unsigned mraw_ = ks_ ? RR[fn_].y : RR[fn_].x;               \
                  int32x4 bvv_ = expand16((mraw_ >> hb16) & 0xFFFFu);         \
                  acc[0][fn_] = __builtin_amdgcn_mfma_i32_32x32x32_i8(        \
                      AR[0][ks_], bvv_, acc[0][fn_], 0, 0, 0);                \
                  acc[1][fn_] = __builtin_amdgcn_mfma_i32_32x32x32_i8(        \
                      AR[1][ks_], bvv_, acc[1][fn_], 0, 0, 0);                \
              } }

    LOAD_STAGE(aA, rA, 0);
    for (int it = 0; it < 32; it += 2) {
        LOAD_STAGE(aB, rB, it + 1);              // it+1 <= 31 always
        COMPUTE_STAGE(aA, rA);
        int itn2 = (it + 2 < 32) ? it + 2 : 31;  // last prefetch harmless
        LOAD_STAGE(aA, rA, itn2);
        COMPUTE_STAGE(aB, rB);
    }
#undef LOAD_STAGE
#undef COMPUTE_STAGE

    // In-register limb combine in wrapping u32 (exact: |s| < 2^31) -> i32.
    int col = lane & 31, h = lane >> 5;
    int* Pk = Pc + (size_t)kc * PPLC32 + (size_t)b * T;
    #pragma unroll
    for (int fm = 0; fm < 2; ++fm) {
        #pragma unroll
        for (int fn = 0; fn < 3; ++fn) {
            if (fn >= nfr) continue;
            int t = (half * 5 + ng0 + fn) * 32 + col;
            if (t >= T) continue;
            int obase = mt * 32 + wm * 16 + fm * 8;
            #pragma unroll
            for (int q = 0; q < 4; ++q) {
                int o = obase + 2 * q + h;
                unsigned s = (unsigned)acc[fm][fn][4 * q]
                           + ((unsigned)acc[fm][fn][4 * q + 1] << 8)
                           + ((unsigned)acc[fm][fn][4 * q + 2] << 16)
                           + ((unsigned)acc[fm][fn][4 * q + 3] << 24);
                Pk[(size_t)o * NCOLS + t] = (int)s;
            }
        }
    }
}

// ---------------------------------------------------------------------------
// Layer 1: sum 8 i32 kc planes in i64 (exact) + psp conv + fused spike LIF.
// smask1: u16[col][28] (== u64[col][7]); slots 26,27 zeroed.
// ---------------------------------------------------------------------------
__global__ __launch_bounds__(320) void redpsp1_kernel(
    const int* __restrict__ Pc, unsigned short* __restrict__ smask)
{
    __shared__ double zs[16][304];
    __shared__ double us[16][304];
    __shared__ double eps[100];
    int og = blockIdx.x, b = blockIdx.y;
    int o0 = og * 16;
    int tid = threadIdx.x;
    const double sc27 = 1.0 / 134217728.0;

    if (tid < 100) {
        double td = (double)tid;
        eps[tid] = (td / 10.0) * exp(1.0 - td / 10.0);
    }
    if (tid < T) {
        size_t col = (size_t)b * T + tid;
        #pragma unroll 4
        for (int ol = 0; ol < 16; ++ol) {
            int o = o0 + ol;
            size_t idx = (size_t)o * NCOLS + col;
            long long s = 0;
            #pragma unroll
            for (int c = 0; c < 8; ++c)
                s += (long long)Pc[(size_t)c * PPLC32 + idx];
            zs[ol][tid] = (double)s * sc27;
        }
    }
    __syncthreads();

    if (tid < T) {
        double sum[16];
        #pragma unroll
        for (int o = 0; o < 16; ++o) sum[o] = 0.0;
        int kmax = tid < 99 ? tid : 99;
        for (int k = 0; k <= kmax; ++k) {
            double e = eps[k];
            #pragma unroll
            for (int o = 0; o < 16; ++o)
                sum[o] = fma(e, zs[o][tid - k], sum[o]);
        }
        #pragma unroll
        for (int o = 0; o < 16; ++o) us[o][tid] = sum[o];
    }
    if (og == 25 && tid < T) {     // zero mask bits 416..447
        size_t col = (size_t)b * T + tid;
        *(unsigned*)((char*)smask + (col * 28 + 26) * 2) = 0u;
    }
    __syncthreads();

    if (tid < 64) {
        int l = tid;
        bool act = (l < 16) && (o0 + l < O1);
        const double alpha = exp(-0.5);
        const double A31   = exp(-15.5);
        const double c0    = -10.0 * exp(1.0);
        double E = 0.0, G = 0.0;
        unsigned hist = 0u;
        for (int t = 0; t < T; ++t) {
            double uval = act ? us[l][t] : -1.0e300;
            double v = uval + c0 * G;
            bool sp = (v >= 10.0);
            unsigned long long bal = __ballot(sp);
            if (l == 0)
                smask[((size_t)b * T + t) * 28 + og] =
                    (unsigned short)(bal & 0xFFFFu);
            double sN  = sp ? 1.0 : 0.0;
            double s31 = ((hist >> 30) & 1u) ? 1.0 : 0.0;
            double Em  = E - A31 * s31;
            double Gm  = G - 31.0 * A31 * s31;
            G = alpha * (sN + Gm + Em);
            E = alpha * (sN + Em);
            hist = (hist << 1) | (sp ? 1u : 0u);
        }
    }
}

// ---------------------------------------------------------------------------
// Layers 2/3: reduce (i32 z, scale) + psp conv + fused spike (round-15).
// ---------------------------------------------------------------------------
template<int OPAD_, int O_, int SLOTS, int NOG, bool OUT>
__global__ __launch_bounds__(320) void redpsp23_kernel(
    const int* __restrict__ Z, unsigned short* __restrict__ smask,
    float* __restrict__ sout, double scale)
{
    __shared__ double zs[16][304];
    __shared__ double us[16][304];
    __shared__ double eps[100];
    int og = blockIdx.x, b = blockIdx.y;
    int o0 = og * 16;
    int tid = threadIdx.x;

    if (tid < 100) {
        double td = (double)tid;
        eps[tid] = (td / 10.0) * exp(1.0 - td / 10.0);
    }
    if (tid < T) {
        size_t col = (size_t)b * T + tid;
        #pragma unroll 4
        for (int ol = 0; ol < 16; ++ol) {
            int o = o0 + ol;
            double zv = (o < OPAD_) ? (double)Z[col * OPAD_ + o] * scale : 0.0;
            zs[ol][tid] = zv;
        }
    }
    __syncthreads();

    if (tid < T) {
        double sum[16];
        #pragma unroll
        for (int o = 0; o < 16; ++o) sum[o] = 0.0;
        int kmax = tid < 99 ? tid : 99;
        for (int k = 0; k <= kmax; ++k) {
            double e = eps[k];
            #pragma unroll
            for (int o = 0; o < 16; ++o)
                sum[o] = fma(e, zs[o][tid - k], sum[o]);
        }
        #pragma unroll
        for (int o = 0; o < 16; ++o) us[o][tid] = sum[o];
    }
    if (SLOTS > NOG && og == NOG - 1 && tid < T) {
        size_t col = (size_t)b * T + tid;
        #pragma unroll
        for (int s = NOG; s < SLOTS; ++s)
            smask[col * SLOTS + s] = 0;
    }
    __syncthreads();

    if (tid < 64) {
        int l = tid;
        bool act = (l < 16) && (o0 + l < O_);
        const double alpha = exp(-0.5);
        const double A31   = exp(-15.5);
        const double c0    = -10.0 * exp(1.0);
        double E = 0.0, G = 0.0;
        unsigned hist = 0u;
        for (int t = 0; t < T; ++t) {
            double uval = act ? us[l][t] : -1.0e300;
            double v = uval + c0 * G;
            bool sp = (v >= 10.0);
            unsigned long long bal = __ballot(sp);
            if (SLOTS > 0 && l == 0)
                smask[((size_t)b * T + t) * SLOTS + og] =
                    (unsigned short)(bal & 0xFFFFu);
            if (OUT && act)
                sout[((size_t)b * O_ + o0 + l) * T + t] = sp ? 1.0f : 0.0f;
            double sN  = sp ? 1.0 : 0.0;
            double s31 = ((hist >> 30) & 1u) ? 1.0 : 0.0;
            double Em  = E - A31 * s31;
            double Gm  = G - 31.0 * A31 * s31;
            G = alpha * (sN + Gm + Em);
            E = alpha * (sN + Em);
            hist = (hist << 1) | (sp ? 1u : 0u);
        }
    }
}

// ---------------------------------------------------------------------------
// Sparse integer GEMM for layers 2/3 (proven).
// ---------------------------------------------------------------------------
__global__ __launch_bounds__(128) void sparse_gemm_kernel(
    const int* __restrict__ QT, const unsigned long long* __restrict__ cmask,
    int* __restrict__ Z, int OPAD, int W, int CW, int cshift)
{
    __shared__ int lf[LCAP];
    __shared__ int wsum[2];

    int chunk = blockIdx.x & ((1 << cshift) - 1);
    int col   = blockIdx.x >> cshift;
    int tid   = threadIdx.x;

    int wbase = col * W + chunk * CW;
    unsigned long long w0 = (2 * tid     < CW) ? cmask[wbase + 2 * tid]     : 0ULL;
    unsigned long long w1 = (2 * tid + 1 < CW) ? cmask[wbase + 2 * tid + 1] : 0ULL;
    int my = __popcll(w0) + __popcll(w1);

    int scan = my;
    #pragma unroll
    for (int d = 1; d < 64; d <<= 1) {
        int v = __shfl_up(scan, d);
        if ((tid & 63) >= d) scan += v;
    }
    if ((tid & 63) == 63) wsum[tid >> 6] = scan;
    __syncthreads();
    int off = ((tid >= 64) ? wsum[0] : 0) + scan - my;
    int n = wsum[0] + wsum[1];

    int f0e = (chunk * CW + 2 * tid) * 64;
    unsigned long long m = w0;
    while (m) {
        int bit = __ffsll(m) - 1;
        if (off < LCAP) lf[off] = (f0e + bit) * OPAD;
        ++off; m &= m - 1;
    }
    m = w1; f0e += 64;
    while (m) {
        int bit = __ffsll(m) - 1;
        if (off < LCAP) lf[off] = (f0e + bit) * OPAD;
        ++off; m &= m - 1;
    }
    __syncthreads();
    if (n > LCAP) n = LCAP;

    if (tid * 4 < OPAD) {
        int o = tid * 4;
        const int* bq = QT + o;
        int a0 = 0, a1 = 0, a2 = 0, a3 = 0;
        int i = 0;
        for (; i + 8 <= n; i += 8) {
            int4 ia = *(const int4*)&lf[i];
            int4 ib = *(const int4*)&lf[i + 4];
            int e0 = __builtin_amdgcn_readfirstlane(ia.x);
            int e1 = __builtin_amdgcn_readfirstlane(ia.y);
            int e2 = __builtin_amdgcn_readfirstlane(ia.z);
            int e3 = __builtin_amdgcn_readfirstlane(ia.w);
            int e4 = __builtin_amdgcn_readfirstlane(ib.x);
            int e5 = __builtin_amdgcn_readfirstlane(ib.y);
            int e6 = __builtin_amdgcn_readfirstlane(ib.z);
            int e7 = __builtin_amdgcn_readfirstlane(ib.w);
            int4 q0 = *(const int4*)(bq + e0);
            int4 q1 = *(const int4*)(bq + e1);
            int4 q2 = *(const int4*)(bq + e2);
            int4 q3 = *(const int4*)(bq + e3);
            int4 q4 = *(const int4*)(bq + e4);
            int4 q5 = *(const int4*)(bq + e5);
            int4 q6 = *(const int4*)(bq + e6);
            int4 q7 = *(const int4*)(bq + e7);
            a0 += q0.x; a1 += q0.y; a2 += q0.z; a3 += q0.w;
            a0 += q1.x; a1 += q1.y; a2 += q1.z; a3 += q1.w;
            a0 += q2.x; a1 += q2.y; a2 += q2.z; a3 += q2.w;
            a0 += q3.x; a1 += q3.y; a2 += q3.z; a3 += q3.w;
            a0 += q4.x; a1 += q4.y; a2 += q4.z; a3 += q4.w;
            a0 += q5.x; a1 += q5.y; a2 += q5.z; a3 += q5.w;
            a0 += q6.x; a1 += q6.y; a2 += q6.z; a3 += q6.w;
            a0 += q7.x; a1 += q7.y; a2 += q7.z; a3 += q7.w;
        }
        for (; i < n; ++i) {
            int e = __builtin_amdgcn_readfirstlane(lf[i]);
            int4 q = *(const int4*)(bq + e);
            a0 += q.x; a1 += q.y; a2 += q.z; a3 += q.w;
        }
        int* zb = Z + ((size_t)chunk * NCOLS + col) * OPAD + o;
        *(int4*)zb = make_int4(a0, a1, a2, a3);
    }
}

// ---------------------------------------------------------------------------
extern "C" void kernel_launch(void* const* d_in, const int* in_sizes, int n_in,
                              void* d_out, int out_size, void* d_ws, size_t ws_size,
                              hipStream_t stream)
{
    const float* x  = (const float*)d_in[0];
    const float* W1 = (const float*)d_in[1];
    const float* W2 = (const float*)d_in[2];
    const float* W3 = (const float*)d_in[3];
    float* out = (float*)d_out;

    const size_t sz_Aswz   = (size_t)13 * 256 * 4 * 2048;      // 27.26 MB
    const size_t sz_Bbit   = (size_t)B * 256 * 320 * 8;        //  5.24 MB
    const size_t sz_Pc     = (size_t)8 * PPLC32 * 4;           // 31.95 MB
    const size_t sz_Q2T    = (size_t)O1 * OP2 * 4;             // 394 KB
    const size_t sz_Q3T    = (size_t)O2 * OP3 * 4;             //  15 KB
    const size_t sz_smask1 = (size_t)NCOLS * 28 * 2;           // 134 KB
    const size_t sz_smask2 = (size_t)NCOLS * 16 * 2;           //  77 KB

    char* p = (char*)d_ws;
    char*               Aswz   = p;                      p += sz_Aswz;
    unsigned long long* Bbit   = (unsigned long long*)p; p += sz_Bbit;
    int*                Pc     = (int*)p;  char* pa = p; p += sz_Pc;
    int*                Q2T    = (int*)p;                p += sz_Q2T;
    int*                Q3T    = (int*)p;                p += sz_Q3T;
    unsigned short*     smask1 = (unsigned short*)p;     p += sz_smask1;
    unsigned short*     smask2 = (unsigned short*)p;     p += sz_smask2;
    // z2/z3 alias Pc's region (Pc dead after redpsp1):
    int* z2 = (int*)pa;                                  pa += (size_t)NCOLS * OP2 * 4;
    int* z3 = (int*)pa;                                  pa += (size_t)NCOLS * OP3 * 4;

    const double sc26 = 1.0 / 67108864.0;

    // --- prep (fused; streaming reads + coalesced mask stores) ---
    prep_kernel<<<dim3(2576), dim3(256), 0, stream>>>(
        x, W1, W2, W3, Bbit, Aswz, Q2T, Q3T);

    // --- layer 1 (MFMA + fused psp/spike) ---
    mfma_gemm_kernel<<<dim3(1664), dim3(256), 0, stream>>>(
        Aswz, (const unsigned short*)Bbit, Pc);
    redpsp1_kernel<<<dim3(26, B), dim3(320), 0, stream>>>(Pc, smask1);

    // --- layer 2 ---
    sparse_gemm_kernel<<<dim3(NCOLS), dim3(128), 0, stream>>>(
        Q2T, (const unsigned long long*)smask1, z2, OP2, W1M, W1M, 0);
    redpsp23_kernel<OP2, O2, 16, 15, false><<<dim3(15, B), dim3(320), 0, stream>>>(
        z2, smask2, (float*)0, sc26);

    // --- layer 3 ---
    sparse_gemm_kernel<<<dim3(NCOLS), dim3(128), 0, stream>>>(
        Q3T, (const unsigned long long*)smask2, z3, OP3, W2M, W2M, 0);
    redpsp23_kernel<OP3, O3, 0, 1, true><<<dim3(1, B), dim3(320), 0, stream>>>(
        z3, (unsigned short*)0, out, sc26);
}

// Round 20
// 252.602 us; speedup vs baseline: 1.4811x; 1.1028x over previous
//
#include <hip/hip_runtime.h>

// ---------------------------------------------------------------------------
// SLAYER SNN on MI355X — layer 1 on i8 MATRIX CORES, exact integer limbs.
//   q[o,f] = rint(W1[o,f]*2^27) == l0 + 256 l1 + 65536 l2 + 2^24 l3 (signed
//   i8 limbs, exact). z*2^27 = sum_l 2^(8l) * (limb_l GEMM x), x in {0,1},
//   v_mfma_i32_32x32x32_i8 (exact). M limb-interleaved (m=o*4+l) -> limbs
//   combine in-register (wrapping u32, exact since |s| < 2^31); 8 i32 kc
//   planes sum exactly in i64 in redpsp1. z integer-identical throughout.
// Round 20 bitpack: LANE = t. Each lane builds its own u64 mask word
//   directly: loop l=0..63, coalesced 256B wave-load of x[f0+l][t0..t0+63],
//   acc |= (v!=0)<<l. No ballot, no LDS, no transpose; reads AND writes
//   coalesced by construction (r17: RMW stores; r18: uncoalesced-read
//   amplification; r19: uncoalesced-read latency — all avoided).
// Everything else: round-15 proven structure.
// ---------------------------------------------------------------------------

#define B   8
#define T   300
#define F0  16384
#define O1  410
#define O2  240
#define OP2 240
#define O3  10
#define OP3 16
#define W1M 7             // u64 words per layer-1 mask (28 u16 slots)
#define W2M 4             // u64 words per layer-2 mask (16 u16 slots)
#define NCOLS (B*T)       // 2400
#define LCAP 2048
#define PPLC32 ((size_t)416 * NCOLS)   // i32 elements per kc plane

typedef int  int32x4  __attribute__((ext_vector_type(4)));
typedef int  int32x16 __attribute__((ext_vector_type(16)));

// 16 bits -> 16 bytes (0/1): byte i = bit i. Exactly the fragment pattern.
__device__ __forceinline__ int32x4 expand16(unsigned m)
{
    int32x4 r;
    r.x = (int)((((m      ) & 15u) * 0x00204081u) & 0x01010101u);
    r.y = (int)((((m >>  4) & 15u) * 0x00204081u) & 0x01010101u);
    r.z = (int)((((m >>  8) & 15u) * 0x00204081u) & 0x01010101u);
    r.w = (int)((((m >> 12) & 15u) * 0x00204081u) & 0x01010101u);
    return r;
}

// ---------------------------------------------------------------------------
// Fused prep: [0,2560) bitpack x (lane=t, direct bit build, all coalesced);
// [2560,4224) quant W1 limbs; [4224,4624) quant W2/W3. No LDS.
// Bbit u64: word (b*256+it)*320 + t, bit l = (x[b][it*64+l][t] != 0).
// ---------------------------------------------------------------------------
__global__ __launch_bounds__(256) void prep_kernel(
    const float* __restrict__ X,  const float* __restrict__ W1,
    const float* __restrict__ W2, const float* __restrict__ W3,
    unsigned long long* __restrict__ Bbit, char* __restrict__ Aswz,
    int* __restrict__ Q2T, int* __restrict__ Q3T)
{
    int bid = blockIdx.x;
    int tid = threadIdx.x;

    if (bid < 2560) {                            // ---- bitpack, lane = t ----
        int wid = bid * 4 + (tid >> 6);          // 0..10239
        int gw = wid / 5, c = wid % 5;           // gw = b*256+it, c = t-chunk
        int b = gw >> 8, it = gw & 255;
        int lane = tid & 63;
        int t = c * 64 + lane;                   // 0..319
        int tc = (t < T) ? t : (T - 1);          // clamped load col (no OOB)

        const float* xp = X + ((size_t)b * F0 + it * 64) * T + tc;
        unsigned long long acc = 0;
        #pragma unroll 8
        for (int l = 0; l < 64; ++l) {
            float v = xp[(size_t)l * T];         // coalesced 256B wave-load
            acc |= (unsigned long long)(v != 0.0f ? 1u : 0u) << l;
        }
        if (t < T)
            Bbit[(size_t)(b * 256 + it) * 320 + t] = acc;   // coalesced store

    } else if (bid < 4224) {                     // ---- quant W1 limbs ----
        int j = bid - 2560;                      // 0..1663
        int o  = j >> 2;
        int f0 = ((j & 3) * 256 + tid) * 16;

        float w[16];
        if (o < O1) {
            #pragma unroll
            for (int e = 0; e < 16; e += 4)
                *(float4*)&w[e] = *(const float4*)(W1 + (size_t)o * F0 + f0 + e);
        } else {
            #pragma unroll
            for (int e = 0; e < 16; ++e) w[e] = 0.0f;
        }

        unsigned pk[4][4] = {{0,0,0,0},{0,0,0,0},{0,0,0,0},{0,0,0,0}};
        #pragma unroll
        for (int e = 0; e < 16; ++e) {
            int q = (int)__double2ll_rn((double)w[e] * 134217728.0);   // 2^27
            int l0 = (int)(signed char)(q & 255);  q = (q - l0) >> 8;
            int l1 = (int)(signed char)(q & 255);  q = (q - l1) >> 8;
            int l2 = (int)(signed char)(q & 255);  int l3 = (q - l2) >> 8;
            pk[0][e >> 2] |= (unsigned)(l0 & 255) << (8 * (e & 3));
            pk[1][e >> 2] |= (unsigned)(l1 & 255) << (8 * (e & 3));
            pk[2][e >> 2] |= (unsigned)(l2 & 255) << (8 * (e & 3));
            pk[3][e >> 2] |= (unsigned)(l3 & 255) << (8 * (e & 3));
        }

        int kit = f0 >> 6, ks = (f0 >> 5) & 1, hb = (f0 >> 4) & 1;
        #pragma unroll
        for (int l = 0; l < 4; ++l) {
            int m = o * 4 + l;
            int mt = m >> 7, r = m & 127, g = r >> 5, row = r & 31;
            int word = ks * 64 + row + 32 * hb;
            size_t addr = ((size_t)(mt * 256 + kit) * 4 + g) * 2048 + (size_t)word * 16;
            *(int32x4*)(Aswz + addr) =
                (int32x4){(int)pk[l][0], (int)pk[l][1], (int)pk[l][2], (int)pk[l][3]};
        }

    } else {                                     // ---- quant W2/W3 ----
        int idx = (bid - 4224) * 256 + tid;
        const int n1 = O1 * OP2;                 // 98400
        const int n2 = O2 * OP3;                 // 3840
        if (idx < n1) {
            int f = idx / OP2, o = idx - f * OP2;
            Q2T[idx] = (int)__double2ll_rn((double)W2[(size_t)o * O1 + f] * 67108864.0);
        } else if (idx < n1 + n2) {
            int j = idx - n1;
            int f = j / OP3, o = j - f * OP3;
            double v = (o < O3) ? (double)W3[(size_t)o * O2 + f] : 0.0;
            Q3T[j] = (int)__double2ll_rn(v * 67108864.0);
        }
    }
}

// ---------------------------------------------------------------------------
// LDS-free i8 MFMA GEMM, copy-free 2-stage pipeline, kc=8 (round-15 proven).
// ---------------------------------------------------------------------------
__global__ __launch_bounds__(256) void mfma_gemm_kernel(
    const char* __restrict__ Aswz, const unsigned short* __restrict__ Bbit,
    int* __restrict__ Pc)
{
    int id  = blockIdx.x;
    int xcd = id & 7, rr = id >> 3;
    int bh  = rr & 15, gq = rr >> 4;
    int g   = xcd + 8 * gq;                      // 0..103, exact
    int mt = g >> 3, kc = g & 7;
    int b = bh >> 1, half = bh & 1;

    int tid = threadIdx.x;
    int lane = tid & 63, wv = tid >> 6;
    int wm = wv >> 1, wn = wv & 1;
    int ng0 = wn * 3;
    int nfr = wn ? 2 : 3;                        // wave-uniform

    const char* Ab = Aswz + ((size_t)(mt * 256 + kc * 32) * 4 + wm * 2) * 2048
                          + (size_t)lane * 16;
    const char* Bb = (const char*)Bbit + (size_t)(b * 256 + kc * 32) * 320 * 8;
    int hb16 = (lane >> 5) * 16;

    const char* Bf[3];
    #pragma unroll
    for (int fn = 0; fn < 3; ++fn) {
        int colf = (half * 5 + ng0 + fn) * 32 + (lane & 31);
        Bf[fn] = Bb + (size_t)colf * 8;
    }

    int32x16 acc[2][3];
    #pragma unroll
    for (int fm = 0; fm < 2; ++fm)
        #pragma unroll
        for (int fn = 0; fn < 3; ++fn)
            acc[fm][fn] = (int32x16){0,0,0,0,0,0,0,0,0,0,0,0,0,0,0,0};

    int32x4 aA[2][2], aB[2][2];
    uint2   rA[3],    rB[3];

#define LOAD_STAGE(AR, RR, ITN)                                               \
    { const char* Abn_ = Ab + (size_t)(ITN) * 8192;                           \
      AR[0][0] = *(const int32x4*)(Abn_);                                     \
      AR[0][1] = *(const int32x4*)(Abn_ + 1024);                              \
      AR[1][0] = *(const int32x4*)(Abn_ + 2048);                              \
      AR[1][1] = *(const int32x4*)(Abn_ + 3072);                              \
      _Pragma("unroll")                                                       \
      for (int fn_ = 0; fn_ < 3; ++fn_)                                       \
          if (fn_ < nfr)                                                      \
              RR[fn_] = *(const uint2*)(Bf[fn_] + (size_t)(ITN) * 2560); }

#define COMPUTE_STAGE(AR, RR)                                                 \
    { _Pragma("unroll")                                                       \
      for (int ks_ = 0; ks_ < 2; ++ks_)                                       \
          _Pragma("unroll")                                                   \
          for (int fn_ = 0; fn_ < 3; ++fn_)                                   \
              if (fn_ < nfr) {                                                \
                  unsigned mraw_ = ks_ ? RR[fn_].y : RR[fn_].x;               \
                  int32x4 bvv_ = expand16((mraw_ >> hb16) & 0xFFFFu);         \
                  acc[0][fn_] = __builtin_amdgcn_mfma_i32_32x32x32_i8(        \
                      AR[0][ks_], bvv_, acc[0][fn_], 0, 0, 0);                \
                  acc[1][fn_] = __builtin_amdgcn_mfma_i32_32x32x32_i8(        \
                      AR[1][ks_], bvv_, acc[1][fn_], 0, 0, 0);                \
              } }

    LOAD_STAGE(aA, rA, 0);
    for (int it = 0; it < 32; it += 2) {
        LOAD_STAGE(aB, rB, it + 1);              // it+1 <= 31 always
        COMPUTE_STAGE(aA, rA);
        int itn2 = (it + 2 < 32) ? it + 2 : 31;  // last prefetch harmless
        LOAD_STAGE(aA, rA, itn2);
        COMPUTE_STAGE(aB, rB);
    }
#undef LOAD_STAGE
#undef COMPUTE_STAGE

    // In-register limb combine in wrapping u32 (exact: |s| < 2^31) -> i32.
    int col = lane & 31, h = lane >> 5;
    int* Pk = Pc + (size_t)kc * PPLC32 + (size_t)b * T;
    #pragma unroll
    for (int fm = 0; fm < 2; ++fm) {
        #pragma unroll
        for (int fn = 0; fn < 3; ++fn) {
            if (fn >= nfr) continue;
            int t = (half * 5 + ng0 + fn) * 32 + col;
            if (t >= T) continue;
            int obase = mt * 32 + wm * 16 + fm * 8;
            #pragma unroll
            for (int q = 0; q < 4; ++q) {
                int o = obase + 2 * q + h;
                unsigned s = (unsigned)acc[fm][fn][4 * q]
                           + ((unsigned)acc[fm][fn][4 * q + 1] << 8)
                           + ((unsigned)acc[fm][fn][4 * q + 2] << 16)
                           + ((unsigned)acc[fm][fn][4 * q + 3] << 24);
                Pk[(size_t)o * NCOLS + t] = (int)s;
            }
        }
    }
}

// ---------------------------------------------------------------------------
// Layer 1: sum 8 i32 kc planes in i64 (exact) + psp conv + fused spike LIF.
// smask1: u16[col][28] (== u64[col][7]); slots 26,27 zeroed.
// ---------------------------------------------------------------------------
__global__ __launch_bounds__(320) void redpsp1_kernel(
    const int* __restrict__ Pc, unsigned short* __restrict__ smask)
{
    __shared__ double zs[16][304];
    __shared__ double us[16][304];
    __shared__ double eps[100];
    int og = blockIdx.x, b = blockIdx.y;
    int o0 = og * 16;
    int tid = threadIdx.x;
    const double sc27 = 1.0 / 134217728.0;

    if (tid < 100) {
        double td = (double)tid;
        eps[tid] = (td / 10.0) * exp(1.0 - td / 10.0);
    }
    if (tid < T) {
        size_t col = (size_t)b * T + tid;
        #pragma unroll 4
        for (int ol = 0; ol < 16; ++ol) {
            int o = o0 + ol;
            size_t idx = (size_t)o * NCOLS + col;
            long long s = 0;
            #pragma unroll
            for (int c = 0; c < 8; ++c)
                s += (long long)Pc[(size_t)c * PPLC32 + idx];
            zs[ol][tid] = (double)s * sc27;
        }
    }
    __syncthreads();

    if (tid < T) {
        double sum[16];
        #pragma unroll
        for (int o = 0; o < 16; ++o) sum[o] = 0.0;
        int kmax = tid < 99 ? tid : 99;
        for (int k = 0; k <= kmax; ++k) {
            double e = eps[k];
            #pragma unroll
            for (int o = 0; o < 16; ++o)
                sum[o] = fma(e, zs[o][tid - k], sum[o]);
        }
        #pragma unroll
        for (int o = 0; o < 16; ++o) us[o][tid] = sum[o];
    }
    if (og == 25 && tid < T) {     // zero mask bits 416..447
        size_t col = (size_t)b * T + tid;
        *(unsigned*)((char*)smask + (col * 28 + 26) * 2) = 0u;
    }
    __syncthreads();

    if (tid < 64) {
        int l = tid;
        bool act = (l < 16) && (o0 + l < O1);
        const double alpha = exp(-0.5);
        const double A31   = exp(-15.5);
        const double c0    = -10.0 * exp(1.0);
        double E = 0.0, G = 0.0;
        unsigned hist = 0u;
        for (int t = 0; t < T; ++t) {
            double uval = act ? us[l][t] : -1.0e300;
            double v = uval + c0 * G;
            bool sp = (v >= 10.0);
            unsigned long long bal = __ballot(sp);
            if (l == 0)
                smask[((size_t)b * T + t) * 28 + og] =
                    (unsigned short)(bal & 0xFFFFu);
            double sN  = sp ? 1.0 : 0.0;
            double s31 = ((hist >> 30) & 1u) ? 1.0 : 0.0;
            double Em  = E - A31 * s31;
            double Gm  = G - 31.0 * A31 * s31;
            G = alpha * (sN + Gm + Em);
            E = alpha * (sN + Em);
            hist = (hist << 1) | (sp ? 1u : 0u);
        }
    }
}

// ---------------------------------------------------------------------------
// Layers 2/3: reduce (i32 z, scale) + psp conv + fused spike (round-15).
// ---------------------------------------------------------------------------
template<int OPAD_, int O_, int SLOTS, int NOG, bool OUT>
__global__ __launch_bounds__(320) void redpsp23_kernel(
    const int* __restrict__ Z, unsigned short* __restrict__ smask,
    float* __restrict__ sout, double scale)
{
    __shared__ double zs[16][304];
    __shared__ double us[16][304];
    __shared__ double eps[100];
    int og = blockIdx.x, b = blockIdx.y;
    int o0 = og * 16;
    int tid = threadIdx.x;

    if (tid < 100) {
        double td = (double)tid;
        eps[tid] = (td / 10.0) * exp(1.0 - td / 10.0);
    }
    if (tid < T) {
        size_t col = (size_t)b * T + tid;
        #pragma unroll 4
        for (int ol = 0; ol < 16; ++ol) {
            int o = o0 + ol;
            double zv = (o < OPAD_) ? (double)Z[col * OPAD_ + o] * scale : 0.0;
            zs[ol][tid] = zv;
        }
    }
    __syncthreads();

    if (tid < T) {
        double sum[16];
        #pragma unroll
        for (int o = 0; o < 16; ++o) sum[o] = 0.0;
        int kmax = tid < 99 ? tid : 99;
        for (int k = 0; k <= kmax; ++k) {
            double e = eps[k];
            #pragma unroll
            for (int o = 0; o < 16; ++o)
                sum[o] = fma(e, zs[o][tid - k], sum[o]);
        }
        #pragma unroll
        for (int o = 0; o < 16; ++o) us[o][tid] = sum[o];
    }
    if (SLOTS > NOG && og == NOG - 1 && tid < T) {
        size_t col = (size_t)b * T + tid;
        #pragma unroll
        for (int s = NOG; s < SLOTS; ++s)
            smask[col * SLOTS + s] = 0;
    }
    __syncthreads();

    if (tid < 64) {
        int l = tid;
        bool act = (l < 16) && (o0 + l < O_);
        const double alpha = exp(-0.5);
        const double A31   = exp(-15.5);
        const double c0    = -10.0 * exp(1.0);
        double E = 0.0, G = 0.0;
        unsigned hist = 0u;
        for (int t = 0; t < T; ++t) {
            double uval = act ? us[l][t] : -1.0e300;
            double v = uval + c0 * G;
            bool sp = (v >= 10.0);
            unsigned long long bal = __ballot(sp);
            if (SLOTS > 0 && l == 0)
                smask[((size_t)b * T + t) * SLOTS + og] =
                    (unsigned short)(bal & 0xFFFFu);
            if (OUT && act)
                sout[((size_t)b * O_ + o0 + l) * T + t] = sp ? 1.0f : 0.0f;
            double sN  = sp ? 1.0 : 0.0;
            double s31 = ((hist >> 30) & 1u) ? 1.0 : 0.0;
            double Em  = E - A31 * s31;
            double Gm  = G - 31.0 * A31 * s31;
            G = alpha * (sN + Gm + Em);
            E = alpha * (sN + Em);
            hist = (hist << 1) | (sp ? 1u : 0u);
        }
    }
}

// ---------------------------------------------------------------------------
// Sparse integer GEMM for layers 2/3 (proven).
// ---------------------------------------------------------------------------
__global__ __launch_bounds__(128) void sparse_gemm_kernel(
    const int* __restrict__ QT, const unsigned long long* __restrict__ cmask,
    int* __restrict__ Z, int OPAD, int W, int CW, int cshift)
{
    __shared__ int lf[LCAP];
    __shared__ int wsum[2];

    int chunk = blockIdx.x & ((1 << cshift) - 1);
    int col   = blockIdx.x >> cshift;
    int tid   = threadIdx.x;

    int wbase = col * W + chunk * CW;
    unsigned long long w0 = (2 * tid     < CW) ? cmask[wbase + 2 * tid]     : 0ULL;
    unsigned long long w1 = (2 * tid + 1 < CW) ? cmask[wbase + 2 * tid + 1] : 0ULL;
    int my = __popcll(w0) + __popcll(w1);

    int scan = my;
    #pragma unroll
    for (int d = 1; d < 64; d <<= 1) {
        int v = __shfl_up(scan, d);
        if ((tid & 63) >= d) scan += v;
    }
    if ((tid & 63) == 63) wsum[tid >> 6] = scan;
    __syncthreads();
    int off = ((tid >= 64) ? wsum[0] : 0) + scan - my;
    int n = wsum[0] + wsum[1];

    int f0e = (chunk * CW + 2 * tid) * 64;
    unsigned long long m = w0;
    while (m) {
        int bit = __ffsll(m) - 1;
        if (off < LCAP) lf[off] = (f0e + bit) * OPAD;
        ++off; m &= m - 1;
    }
    m = w1; f0e += 64;
    while (m) {
        int bit = __ffsll(m) - 1;
        if (off < LCAP) lf[off] = (f0e + bit) * OPAD;
        ++off; m &= m - 1;
    }
    __syncthreads();
    if (n > LCAP) n = LCAP;

    if (tid * 4 < OPAD) {
        int o = tid * 4;
        const int* bq = QT + o;
        int a0 = 0, a1 = 0, a2 = 0, a3 = 0;
        int i = 0;
        for (; i + 8 <= n; i += 8) {
            int4 ia = *(const int4*)&lf[i];
            int4 ib = *(const int4*)&lf[i + 4];
            int e0 = __builtin_amdgcn_readfirstlane(ia.x);
            int e1 = __builtin_amdgcn_readfirstlane(ia.y);
            int e2 = __builtin_amdgcn_readfirstlane(ia.z);
            int e3 = __builtin_amdgcn_readfirstlane(ia.w);
            int e4 = __builtin_amdgcn_readfirstlane(ib.x);
            int e5 = __builtin_amdgcn_readfirstlane(ib.y);
            int e6 = __builtin_amdgcn_readfirstlane(ib.z);
            int e7 = __builtin_amdgcn_readfirstlane(ib.w);
            int4 q0 = *(const int4*)(bq + e0);
            int4 q1 = *(const int4*)(bq + e1);
            int4 q2 = *(const int4*)(bq + e2);
            int4 q3 = *(const int4*)(bq + e3);
            int4 q4 = *(const int4*)(bq + e4);
            int4 q5 = *(const int4*)(bq + e5);
            int4 q6 = *(const int4*)(bq + e6);
            int4 q7 = *(const int4*)(bq + e7);
            a0 += q0.x; a1 += q0.y; a2 += q0.z; a3 += q0.w;
            a0 += q1.x; a1 += q1.y; a2 += q1.z; a3 += q1.w;
            a0 += q2.x; a1 += q2.y; a2 += q2.z; a3 += q2.w;
            a0 += q3.x; a1 += q3.y; a2 += q3.z; a3 += q3.w;
            a0 += q4.x; a1 += q4.y; a2 += q4.z; a3 += q4.w;
            a0 += q5.x; a1 += q5.y; a2 += q5.z; a3 += q5.w;
            a0 += q6.x; a1 += q6.y; a2 += q6.z; a3 += q6.w;
            a0 += q7.x; a1 += q7.y; a2 += q7.z; a3 += q7.w;
        }
        for (; i < n; ++i) {
            int e = __builtin_amdgcn_readfirstlane(lf[i]);
            int4 q = *(const int4*)(bq + e);
            a0 += q.x; a1 += q.y; a2 += q.z; a3 += q.w;
        }
        int* zb = Z + ((size_t)chunk * NCOLS + col) * OPAD + o;
        *(int4*)zb = make_int4(a0, a1, a2, a3);
    }
}

// ---------------------------------------------------------------------------
extern "C" void kernel_launch(void* const* d_in, const int* in_sizes, int n_in,
                              void* d_out, int out_size, void* d_ws, size_t ws_size,
                              hipStream_t stream)
{
    const float* x  = (const float*)d_in[0];
    const float* W1 = (const float*)d_in[1];
    const float* W2 = (const float*)d_in[2];
    const float* W3 = (const float*)d_in[3];
    float* out = (float*)d_out;

    const size_t sz_Aswz   = (size_t)13 * 256 * 4 * 2048;      // 27.26 MB
    const size_t sz_Bbit   = (size_t)B * 256 * 320 * 8;        //  5.24 MB
    const size_t sz_Pc     = (size_t)8 * PPLC32 * 4;           // 31.95 MB
    const size_t sz_Q2T    = (size_t)O1 * OP2 * 4;             // 394 KB
    const size_t sz_Q3T    = (size_t)O2 * OP3 * 4;             //  15 KB
    const size_t sz_smask1 = (size_t)NCOLS * 28 * 2;           // 134 KB
    const size_t sz_smask2 = (size_t)NCOLS * 16 * 2;           //  77 KB

    char* p = (char*)d_ws;
    char*               Aswz   = p;                      p += sz_Aswz;
    unsigned long long* Bbit   = (unsigned long long*)p; p += sz_Bbit;
    int*                Pc     = (int*)p;  char* pa = p; p += sz_Pc;
    int*                Q2T    = (int*)p;                p += sz_Q2T;
    int*                Q3T    = (int*)p;                p += sz_Q3T;
    unsigned short*     smask1 = (unsigned short*)p;     p += sz_smask1;
    unsigned short*     smask2 = (unsigned short*)p;     p += sz_smask2;
    // z2/z3 alias Pc's region (Pc dead after redpsp1):
    int* z2 = (int*)pa;                                  pa += (size_t)NCOLS * OP2 * 4;
    int* z3 = (int*)pa;                                  pa += (size_t)NCOLS * OP3 * 4;

    const double sc26 = 1.0 / 67108864.0;

    // --- prep (fused; all-coalesced direct bitpack) ---
    prep_kernel<<<dim3(4624), dim3(256), 0, stream>>>(
        x, W1, W2, W3, Bbit, Aswz, Q2T, Q3T);

    // --- layer 1 (MFMA + fused psp/spike) ---
    mfma_gemm_kernel<<<dim3(1664), dim3(256), 0, stream>>>(
        Aswz, (const unsigned short*)Bbit, Pc);
    redpsp1_kernel<<<dim3(26, B), dim3(320), 0, stream>>>(Pc, smask1);

    // --- layer 2 ---
    sparse_gemm_kernel<<<dim3(NCOLS), dim3(128), 0, stream>>>(
        Q2T, (const unsigned long long*)smask1, z2, OP2, W1M, W1M, 0);
    redpsp23_kernel<OP2, O2, 16, 15, false><<<dim3(15, B), dim3(320), 0, stream>>>(
        z2, smask2, (float*)0, sc26);

    // --- layer 3 ---
    sparse_gemm_kernel<<<dim3(NCOLS), dim3(128), 0, stream>>>(
        Q3T, (const unsigned long long*)smask2, z3, OP3, W2M, W2M, 0);
    redpsp23_kernel<OP3, O3, 0, 1, true><<<dim3(1, B), dim3(320), 0, stream>>>(
        z3, (unsigned short*)0, out, sc26);
}

// Round 21
// 249.879 us; speedup vs baseline: 1.4973x; 1.0109x over previous
//
#include <hip/hip_runtime.h>

// ---------------------------------------------------------------------------
// SLAYER SNN on MI355X — layer 1 on i8 MATRIX CORES, exact integer limbs.
//   q[o,f] = rint(W1[o,f]*2^27) == l0 + 256 l1 + 65536 l2 + 2^24 l3 (signed
//   i8 limbs, exact). z*2^27 = sum_l 2^(8l) * (limb_l GEMM x), x in {0,1},
//   v_mfma_i32_32x32x32_i8 (exact). M limb-interleaved (m=o*4+l) -> limbs
//   combine in-register (wrapping u32, exact since |s| < 2^31); 8 i32 kc
//   planes sum exactly in i64 in redpsp1. z integer-identical throughout.
// Round 21 bitpack: thread = t-QUAD with float4 loads (16B/lane, the
//   coalescing sweet spot; round-20's 4B/lane dword loads ran at 1.2 TB/s).
//   Thread accumulates 4 mask words over l=0..63, stores 32B contiguous.
//   Bits identical to all passing rounds.
// Everything else: round-20 proven structure (252.6us best).
// ---------------------------------------------------------------------------

#define B   8
#define T   300
#define F0  16384
#define O1  410
#define O2  240
#define OP2 240
#define O3  10
#define OP3 16
#define W1M 7             // u64 words per layer-1 mask (28 u16 slots)
#define W2M 4             // u64 words per layer-2 mask (16 u16 slots)
#define NCOLS (B*T)       // 2400
#define LCAP 2048
#define PPLC32 ((size_t)416 * NCOLS)   // i32 elements per kc plane

typedef int  int32x4  __attribute__((ext_vector_type(4)));
typedef int  int32x16 __attribute__((ext_vector_type(16)));

// 16 bits -> 16 bytes (0/1): byte i = bit i. Exactly the fragment pattern.
__device__ __forceinline__ int32x4 expand16(unsigned m)
{
    int32x4 r;
    r.x = (int)((((m      ) & 15u) * 0x00204081u) & 0x01010101u);
    r.y = (int)((((m >>  4) & 15u) * 0x00204081u) & 0x01010101u);
    r.z = (int)((((m >>  8) & 15u) * 0x00204081u) & 0x01010101u);
    r.w = (int)((((m >> 12) & 15u) * 0x00204081u) & 0x01010101u);
    return r;
}

// ---------------------------------------------------------------------------
// Fused prep: [0,600) bitpack x (thread = t-quad, float4 loads, 4 mask words
// per thread); [600,2264) quant W1 limbs; [2264,2664) quant W2/W3. No LDS.
// Bbit u64: word (b*256+it)*320 + t, bit l = (x[b][it*64+l][t] != 0).
// ---------------------------------------------------------------------------
__global__ __launch_bounds__(256) void prep_kernel(
    const float* __restrict__ X,  const float* __restrict__ W1,
    const float* __restrict__ W2, const float* __restrict__ W3,
    unsigned long long* __restrict__ Bbit, char* __restrict__ Aswz,
    int* __restrict__ Q2T, int* __restrict__ Q3T)
{
    int bid = blockIdx.x;
    int tid = threadIdx.x;

    if (bid < 600) {                             // ---- bitpack, thread=t-quad
        int g = bid * 256 + tid;                 // 0..153599
        int group = g / 75, tq = g - group * 75; // group = b*256+it, tq 0..74
        int b = group >> 8, it = group & 255;

        const float* xp = X + ((size_t)b * F0 + it * 64) * T + tq * 4;
        unsigned long long a0 = 0, a1 = 0, a2 = 0, a3 = 0;
        #pragma unroll 8
        for (int l = 0; l < 64; ++l) {
            float4 v = *(const float4*)(xp + (size_t)l * T);  // 16B/lane
            unsigned long long bit = 1ULL << l;
            if (v.x != 0.0f) a0 |= bit;
            if (v.y != 0.0f) a1 |= bit;
            if (v.z != 0.0f) a2 |= bit;
            if (v.w != 0.0f) a3 |= bit;
        }
        unsigned long long* dst = Bbit + (size_t)group * 320 + tq * 4;
        dst[0] = a0; dst[1] = a1; dst[2] = a2; dst[3] = a3;   // 32B contiguous

    } else if (bid < 2264) {                     // ---- quant W1 limbs ----
        int j = bid - 600;                       // 0..1663
        int o  = j >> 2;
        int f0 = ((j & 3) * 256 + tid) * 16;

        float w[16];
        if (o < O1) {
            #pragma unroll
            for (int e = 0; e < 16; e += 4)
                *(float4*)&w[e] = *(const float4*)(W1 + (size_t)o * F0 + f0 + e);
        } else {
            #pragma unroll
            for (int e = 0; e < 16; ++e) w[e] = 0.0f;
        }

        unsigned pk[4][4] = {{0,0,0,0},{0,0,0,0},{0,0,0,0},{0,0,0,0}};
        #pragma unroll
        for (int e = 0; e < 16; ++e) {
            int q = (int)__double2ll_rn((double)w[e] * 134217728.0);   // 2^27
            int l0 = (int)(signed char)(q & 255);  q = (q - l0) >> 8;
            int l1 = (int)(signed char)(q & 255);  q = (q - l1) >> 8;
            int l2 = (int)(signed char)(q & 255);  int l3 = (q - l2) >> 8;
            pk[0][e >> 2] |= (unsigned)(l0 & 255) << (8 * (e & 3));
            pk[1][e >> 2] |= (unsigned)(l1 & 255) << (8 * (e & 3));
            pk[2][e >> 2] |= (unsigned)(l2 & 255) << (8 * (e & 3));
            pk[3][e >> 2] |= (unsigned)(l3 & 255) << (8 * (e & 3));
        }

        int kit = f0 >> 6, ks = (f0 >> 5) & 1, hb = (f0 >> 4) & 1;
        #pragma unroll
        for (int l = 0; l < 4; ++l) {
            int m = o * 4 + l;
            int mt = m >> 7, r = m & 127, g2 = r >> 5, row = r & 31;
            int word = ks * 64 + row + 32 * hb;
            size_t addr = ((size_t)(mt * 256 + kit) * 4 + g2) * 2048 + (size_t)word * 16;
            *(int32x4*)(Aswz + addr) =
                (int32x4){(int)pk[l][0], (int)pk[l][1], (int)pk[l][2], (int)pk[l][3]};
        }

    } else {                                     // ---- quant W2/W3 ----
        int idx = (bid - 2264) * 256 + tid;
        const int n1 = O1 * OP2;                 // 98400
        const int n2 = O2 * OP3;                 // 3840
        if (idx < n1) {
            int f = idx / OP2, o = idx - f * OP2;
            Q2T[idx] = (int)__double2ll_rn((double)W2[(size_t)o * O1 + f] * 67108864.0);
        } else if (idx < n1 + n2) {
            int j = idx - n1;
            int f = j / OP3, o = j - f * OP3;
            double v = (o < O3) ? (double)W3[(size_t)o * O2 + f] : 0.0;
            Q3T[j] = (int)__double2ll_rn(v * 67108864.0);
        }
    }
}

// ---------------------------------------------------------------------------
// LDS-free i8 MFMA GEMM, copy-free 2-stage pipeline, kc=8 (round-15 proven).
// ---------------------------------------------------------------------------
__global__ __launch_bounds__(256) void mfma_gemm_kernel(
    const char* __restrict__ Aswz, const unsigned short* __restrict__ Bbit,
    int* __restrict__ Pc)
{
    int id  = blockIdx.x;
    int xcd = id & 7, rr = id >> 3;
    int bh  = rr & 15, gq = rr >> 4;
    int g   = xcd + 8 * gq;                      // 0..103, exact
    int mt = g >> 3, kc = g & 7;
    int b = bh >> 1, half = bh & 1;

    int tid = threadIdx.x;
    int lane = tid & 63, wv = tid >> 6;
    int wm = wv >> 1, wn = wv & 1;
    int ng0 = wn * 3;
    int nfr = wn ? 2 : 3;                        // wave-uniform

    const char* Ab = Aswz + ((size_t)(mt * 256 + kc * 32) * 4 + wm * 2) * 2048
                          + (size_t)lane * 16;
    const char* Bb = (const char*)Bbit + (size_t)(b * 256 + kc * 32) * 320 * 8;
    int hb16 = (lane >> 5) * 16;

    const char* Bf[3];
    #pragma unroll
    for (int fn = 0; fn < 3; ++fn) {
        int colf = (half * 5 + ng0 + fn) * 32 + (lane & 31);
        Bf[fn] = Bb + (size_t)colf * 8;
    }

    int32x16 acc[2][3];
    #pragma unroll
    for (int fm = 0; fm < 2; ++fm)
        #pragma unroll
        for (int fn = 0; fn < 3; ++fn)
            acc[fm][fn] = (int32x16){0,0,0,0,0,0,0,0,0,0,0,0,0,0,0,0};

    int32x4 aA[2][2], aB[2][2];
    uint2   rA[3],    rB[3];

#define LOAD_STAGE(AR, RR, ITN)                                               \
    { const char* Abn_ = Ab + (size_t)(ITN) * 8192;                           \
      AR[0][0] = *(const int32x4*)(Abn_);                                     \
      AR[0][1] = *(const int32x4*)(Abn_ + 1024);                              \
      AR[1][0] = *(const int32x4*)(Abn_ + 2048);                              \
      AR[1][1] = *(const int32x4*)(Abn_ + 3072);                              \
      _Pragma("unroll")                                                       \
      for (int fn_ = 0; fn_ < 3; ++fn_)                                       \
          if (fn_ < nfr)                                                      \
              RR[fn_] = *(const uint2*)(Bf[fn_] + (size_t)(ITN) * 2560); }

#define COMPUTE_STAGE(AR, RR)                                                 \
    { _Pragma("unroll")                                                       \
      for (int ks_ = 0; ks_ < 2; ++ks_)                                       \
          _Pragma("unroll")                                                   \
          for (int fn_ = 0; fn_ < 3; ++fn_)                                   \
              if (fn_ < nfr) {                                                \
                  unsigned mraw_ = ks_ ? RR[fn_].y : RR[fn_].x;               \
                  int32x4 bvv_ = expand16((mraw_ >> hb16) & 0xFFFFu);         \
                  acc[0][fn_] = __builtin_amdgcn_mfma_i32_32x32x32_i8(        \
                      AR[0][ks_], bvv_, acc[0][fn_], 0, 0, 0);                \
                  acc[1][fn_] = __builtin_amdgcn_mfma_i32_32x32x32_i8(        \
                      AR[1][ks_], bvv_, acc[1][fn_], 0, 0, 0);                \
              } }

    LOAD_STAGE(aA, rA, 0);
    for (int it = 0; it < 32; it += 2) {
        LOAD_STAGE(aB, rB, it + 1);              // it+1 <= 31 always
        COMPUTE_STAGE(aA, rA);
        int itn2 = (it + 2 < 32) ? it + 2 : 31;  // last prefetch harmless
        LOAD_STAGE(aA, rA, itn2);
        COMPUTE_STAGE(aB, rB);
    }
#undef LOAD_STAGE
#undef COMPUTE_STAGE

    // In-register limb combine in wrapping u32 (exact: |s| < 2^31) -> i32.
    int col = lane & 31, h = lane >> 5;
    int* Pk = Pc + (size_t)kc * PPLC32 + (size_t)b * T;
    #pragma unroll
    for (int fm = 0; fm < 2; ++fm) {
        #pragma unroll
        for (int fn = 0; fn < 3; ++fn) {
            if (fn >= nfr) continue;
            int t = (half * 5 + ng0 + fn) * 32 + col;
            if (t >= T) continue;
            int obase = mt * 32 + wm * 16 + fm * 8;
            #pragma unroll
            for (int q = 0; q < 4; ++q) {
                int o = obase + 2 * q + h;
                unsigned s = (unsigned)acc[fm][fn][4 * q]
                           + ((unsigned)acc[fm][fn][4 * q + 1] << 8)
                           + ((unsigned)acc[fm][fn][4 * q + 2] << 16)
                           + ((unsigned)acc[fm][fn][4 * q + 3] << 24);
                Pk[(size_t)o * NCOLS + t] = (int)s;
            }
        }
    }
}

// ---------------------------------------------------------------------------
// Layer 1: sum 8 i32 kc planes in i64 (exact) + psp conv + fused spike LIF.
// smask1: u16[col][28] (== u64[col][7]); slots 26,27 zeroed.
// ---------------------------------------------------------------------------
__global__ __launch_bounds__(320) void redpsp1_kernel(
    const int* __restrict__ Pc, unsigned short* __restrict__ smask)
{
    __shared__ double zs[16][304];
    __shared__ double us[16][304];
    __shared__ double eps[100];
    int og = blockIdx.x, b = blockIdx.y;
    int o0 = og * 16;
    int tid = threadIdx.x;
    const double sc27 = 1.0 / 134217728.0;

    if (tid < 100) {
        double td = (double)tid;
        eps[tid] = (td / 10.0) * exp(1.0 - td / 10.0);
    }
    if (tid < T) {
        size_t col = (size_t)b * T + tid;
        #pragma unroll 4
        for (int ol = 0; ol < 16; ++ol) {
            int o = o0 + ol;
            size_t idx = (size_t)o * NCOLS + col;
            long long s = 0;
            #pragma unroll
            for (int c = 0; c < 8; ++c)
                s += (long long)Pc[(size_t)c * PPLC32 + idx];
            zs[ol][tid] = (double)s * sc27;
        }
    }
    __syncthreads();

    if (tid < T) {
        double sum[16];
        #pragma unroll
        for (int o = 0; o < 16; ++o) sum[o] = 0.0;
        int kmax = tid < 99 ? tid : 99;
        for (int k = 0; k <= kmax; ++k) {
            double e = eps[k];
            #pragma unroll
            for (int o = 0; o < 16; ++o)
                sum[o] = fma(e, zs[o][tid - k], sum[o]);
        }
        #pragma unroll
        for (int o = 0; o < 16; ++o) us[o][tid] = sum[o];
    }
    if (og == 25 && tid < T) {     // zero mask bits 416..447
        size_t col = (size_t)b * T + tid;
        *(unsigned*)((char*)smask + (col * 28 + 26) * 2) = 0u;
    }
    __syncthreads();

    if (tid < 64) {
        int l = tid;
        bool act = (l < 16) && (o0 + l < O1);
        const double alpha = exp(-0.5);
        const double A31   = exp(-15.5);
        const double c0    = -10.0 * exp(1.0);
        double E = 0.0, G = 0.0;
        unsigned hist = 0u;
        for (int t = 0; t < T; ++t) {
            double uval = act ? us[l][t] : -1.0e300;
            double v = uval + c0 * G;
            bool sp = (v >= 10.0);
            unsigned long long bal = __ballot(sp);
            if (l == 0)
                smask[((size_t)b * T + t) * 28 + og] =
                    (unsigned short)(bal & 0xFFFFu);
            double sN  = sp ? 1.0 : 0.0;
            double s31 = ((hist >> 30) & 1u) ? 1.0 : 0.0;
            double Em  = E - A31 * s31;
            double Gm  = G - 31.0 * A31 * s31;
            G = alpha * (sN + Gm + Em);
            E = alpha * (sN + Em);
            hist = (hist << 1) | (sp ? 1u : 0u);
        }
    }
}

// ---------------------------------------------------------------------------
// Layers 2/3: reduce (i32 z, scale) + psp conv + fused spike (round-15).
// ---------------------------------------------------------------------------
template<int OPAD_, int O_, int SLOTS, int NOG, bool OUT>
__global__ __launch_bounds__(320) void redpsp23_kernel(
    const int* __restrict__ Z, unsigned short* __restrict__ smask,
    float* __restrict__ sout, double scale)
{
    __shared__ double zs[16][304];
    __shared__ double us[16][304];
    __shared__ double eps[100];
    int og = blockIdx.x, b = blockIdx.y;
    int o0 = og * 16;
    int tid = threadIdx.x;

    if (tid < 100) {
        double td = (double)tid;
        eps[tid] = (td / 10.0) * exp(1.0 - td / 10.0);
    }
    if (tid < T) {
        size_t col = (size_t)b * T + tid;
        #pragma unroll 4
        for (int ol = 0; ol < 16; ++ol) {
            int o = o0 + ol;
            double zv = (o < OPAD_) ? (double)Z[col * OPAD_ + o] * scale : 0.0;
            zs[ol][tid] = zv;
        }
    }
    __syncthreads();

    if (tid < T) {
        double sum[16];
        #pragma unroll
        for (int o = 0; o < 16; ++o) sum[o] = 0.0;
        int kmax = tid < 99 ? tid : 99;
        for (int k = 0; k <= kmax; ++k) {
            double e = eps[k];
            #pragma unroll
            for (int o = 0; o < 16; ++o)
                sum[o] = fma(e, zs[o][tid - k], sum[o]);
        }
        #pragma unroll
        for (int o = 0; o < 16; ++o) us[o][tid] = sum[o];
    }
    if (SLOTS > NOG && og == NOG - 1 && tid < T) {
        size_t col = (size_t)b * T + tid;
        #pragma unroll
        for (int s = NOG; s < SLOTS; ++s)
            smask[col * SLOTS + s] = 0;
    }
    __syncthreads();

    if (tid < 64) {
        int l = tid;
        bool act = (l < 16) && (o0 + l < O_);
        const double alpha = exp(-0.5);
        const double A31   = exp(-15.5);
        const double c0    = -10.0 * exp(1.0);
        double E = 0.0, G = 0.0;
        unsigned hist = 0u;
        for (int t = 0; t < T; ++t) {
            double uval = act ? us[l][t] : -1.0e300;
            double v = uval + c0 * G;
            bool sp = (v >= 10.0);
            unsigned long long bal = __ballot(sp);
            if (SLOTS > 0 && l == 0)
                smask[((size_t)b * T + t) * SLOTS + og] =
                    (unsigned short)(bal & 0xFFFFu);
            if (OUT && act)
                sout[((size_t)b * O_ + o0 + l) * T + t] = sp ? 1.0f : 0.0f;
            double sN  = sp ? 1.0 : 0.0;
            double s31 = ((hist >> 30) & 1u) ? 1.0 : 0.0;
            double Em  = E - A31 * s31;
            double Gm  = G - 31.0 * A31 * s31;
            G = alpha * (sN + Gm + Em);
            E = alpha * (sN + Em);
            hist = (hist << 1) | (sp ? 1u : 0u);
        }
    }
}

// ---------------------------------------------------------------------------
// Sparse integer GEMM for layers 2/3 (proven).
// ---------------------------------------------------------------------------
__global__ __launch_bounds__(128) void sparse_gemm_kernel(
    const int* __restrict__ QT, const unsigned long long* __restrict__ cmask,
    int* __restrict__ Z, int OPAD, int W, int CW, int cshift)
{
    __shared__ int lf[LCAP];
    __shared__ int wsum[2];

    int chunk = blockIdx.x & ((1 << cshift) - 1);
    int col   = blockIdx.x >> cshift;
    int tid   = threadIdx.x;

    int wbase = col * W + chunk * CW;
    unsigned long long w0 = (2 * tid     < CW) ? cmask[wbase + 2 * tid]     : 0ULL;
    unsigned long long w1 = (2 * tid + 1 < CW) ? cmask[wbase + 2 * tid + 1] : 0ULL;
    int my = __popcll(w0) + __popcll(w1);

    int scan = my;
    #pragma unroll
    for (int d = 1; d < 64; d <<= 1) {
        int v = __shfl_up(scan, d);
        if ((tid & 63) >= d) scan += v;
    }
    if ((tid & 63) == 63) wsum[tid >> 6] = scan;
    __syncthreads();
    int off = ((tid >= 64) ? wsum[0] : 0) + scan - my;
    int n = wsum[0] + wsum[1];

    int f0e = (chunk * CW + 2 * tid) * 64;
    unsigned long long m = w0;
    while (m) {
        int bit = __ffsll(m) - 1;
        if (off < LCAP) lf[off] = (f0e + bit) * OPAD;
        ++off; m &= m - 1;
    }
    m = w1; f0e += 64;
    while (m) {
        int bit = __ffsll(m) - 1;
        if (off < LCAP) lf[off] = (f0e + bit) * OPAD;
        ++off; m &= m - 1;
    }
    __syncthreads();
    if (n > LCAP) n = LCAP;

    if (tid * 4 < OPAD) {
        int o = tid * 4;
        const int* bq = QT + o;
        int a0 = 0, a1 = 0, a2 = 0, a3 = 0;
        int i = 0;
        for (; i + 8 <= n; i += 8) {
            int4 ia = *(const int4*)&lf[i];
            int4 ib = *(const int4*)&lf[i + 4];
            int e0 = __builtin_amdgcn_readfirstlane(ia.x);
            int e1 = __builtin_amdgcn_readfirstlane(ia.y);
            int e2 = __builtin_amdgcn_readfirstlane(ia.z);
            int e3 = __builtin_amdgcn_readfirstlane(ia.w);
            int e4 = __builtin_amdgcn_readfirstlane(ib.x);
            int e5 = __builtin_amdgcn_readfirstlane(ib.y);
            int e6 = __builtin_amdgcn_readfirstlane(ib.z);
            int e7 = __builtin_amdgcn_readfirstlane(ib.w);
            int4 q0 = *(const int4*)(bq + e0);
            int4 q1 = *(const int4*)(bq + e1);
            int4 q2 = *(const int4*)(bq + e2);
            int4 q3 = *(const int4*)(bq + e3);
            int4 q4 = *(const int4*)(bq + e4);
            int4 q5 = *(const int4*)(bq + e5);
            int4 q6 = *(const int4*)(bq + e6);
            int4 q7 = *(const int4*)(bq + e7);
            a0 += q0.x; a1 += q0.y; a2 += q0.z; a3 += q0.w;
            a0 += q1.x; a1 += q1.y; a2 += q1.z; a3 += q1.w;
            a0 += q2.x; a1 += q2.y; a2 += q2.z; a3 += q2.w;
            a0 += q3.x; a1 += q3.y; a2 += q3.z; a3 += q3.w;
            a0 += q4.x; a1 += q4.y; a2 += q4.z; a3 += q4.w;
            a0 += q5.x; a1 += q5.y; a2 += q5.z; a3 += q5.w;
            a0 += q6.x; a1 += q6.y; a2 += q6.z; a3 += q6.w;
            a0 += q7.x; a1 += q7.y; a2 += q7.z; a3 += q7.w;
        }
        for (; i < n; ++i) {
            int e = __builtin_amdgcn_readfirstlane(lf[i]);
            int4 q = *(const int4*)(bq + e);
            a0 += q.x; a1 += q.y; a2 += q.z; a3 += q.w;
        }
        int* zb = Z + ((size_t)chunk * NCOLS + col) * OPAD + o;
        *(int4*)zb = make_int4(a0, a1, a2, a3);
    }
}

// ---------------------------------------------------------------------------
extern "C" void kernel_launch(void* const* d_in, const int* in_sizes, int n_in,
                              void* d_out, int out_size, void* d_ws, size_t ws_size,
                              hipStream_t stream)
{
    const float* x  = (const float*)d_in[0];
    const float* W1 = (const float*)d_in[1];
    const float* W2 = (const float*)d_in[2];
    const float* W3 = (const float*)d_in[3];
    float* out = (float*)d_out;

    const size_t sz_Aswz   = (size_t)13 * 256 * 4 * 2048;      // 27.26 MB
    const size_t sz_Bbit   = (size_t)B * 256 * 320 * 8;        //  5.24 MB
    const size_t sz_Pc     = (size_t)8 * PPLC32 * 4;           // 31.95 MB
    const size_t sz_Q2T    = (size_t)O1 * OP2 * 4;             // 394 KB
    const size_t sz_Q3T    = (size_t)O2 * OP3 * 4;             //  15 KB
    const size_t sz_smask1 = (size_t)NCOLS * 28 * 2;           // 134 KB
    const size_t sz_smask2 = (size_t)NCOLS * 16 * 2;           //  77 KB

    char* p = (char*)d_ws;
    char*               Aswz   = p;                      p += sz_Aswz;
    unsigned long long* Bbit   = (unsigned long long*)p; p += sz_Bbit;
    int*                Pc     = (int*)p;  char* pa = p; p += sz_Pc;
    int*                Q2T    = (int*)p;                p += sz_Q2T;
    int*                Q3T    = (int*)p;                p += sz_Q3T;
    unsigned short*     smask1 = (unsigned short*)p;     p += sz_smask1;
    unsigned short*     smask2 = (unsigned short*)p;     p += sz_smask2;
    // z2/z3 alias Pc's region (Pc dead after redpsp1):
    int* z2 = (int*)pa;                                  pa += (size_t)NCOLS * OP2 * 4;
    int* z3 = (int*)pa;                                  pa += (size_t)NCOLS * OP3 * 4;

    const double sc26 = 1.0 / 67108864.0;

    // --- prep (fused; float4 t-quad bitpack, all coalesced) ---
    prep_kernel<<<dim3(2664), dim3(256), 0, stream>>>(
        x, W1, W2, W3, Bbit, Aswz, Q2T, Q3T);

    // --- layer 1 (MFMA + fused psp/spike) ---
    mfma_gemm_kernel<<<dim3(1664), dim3(256), 0, stream>>>(
        Aswz, (const unsigned short*)Bbit, Pc);
    redpsp1_kernel<<<dim3(26, B), dim3(320), 0, stream>>>(Pc, smask1);

    // --- layer 2 ---
    sparse_gemm_kernel<<<dim3(NCOLS), dim3(128), 0, stream>>>(
        Q2T, (const unsigned long long*)smask1, z2, OP2, W1M, W1M, 0);
    redpsp23_kernel<OP2, O2, 16, 15, false><<<dim3(15, B), dim3(320), 0, stream>>>(
        z2, smask2, (float*)0, sc26);

    // --- layer 3 ---
    sparse_gemm_kernel<<<dim3(NCOLS), dim3(128), 0, stream>>>(
        Q3T, (const unsigned long long*)smask2, z3, OP3, W2M, W2M, 0);
    redpsp23_kernel<OP3, O3, 0, 1, true><<<dim3(1, B), dim3(320), 0, stream>>>(
        z3, (unsigned short*)0, out, sc26);
}